// Round 1
// baseline (7223.009 us; speedup 1.0000x reference)
//
#include <hip/hip_runtime.h>
#include <hip/hip_bf16.h>
#include <math.h>

// ---------------------------------------------------------------------------
// CapsuleNet forward, fp32 baseline.
// Pipeline: conv0(relu) -> conv1(relu) -> prim conv -> squash -> routing1 ->
//           routing2 -> classes/softmax/argmax -> z -> 3-layer decoder.
// ---------------------------------------------------------------------------

#define NB 32  // batch

// ---------- weight transpose: w[oc][ic][9][9] -> wt[(ic*81+k)*256 + oc] -----
__global__ void transpose_w_kernel(const float* __restrict__ w,
                                   float* __restrict__ wt, int n) {
  for (int idx = blockIdx.x * blockDim.x + threadIdx.x; idx < n;
       idx += gridDim.x * blockDim.x) {
    int oc  = idx / (256 * 81);
    int rem = idx - oc * (256 * 81);   // ic*81 + k
    wt[rem * 256 + oc] = w[idx];
  }
}

// ---------- conv0: x[32][1][61][61] -> h0[32][256][27][27], k9 s2, relu -----
__global__ __launch_bounds__(256) void conv0_kernel(
    const float* __restrict__ x, const float* __restrict__ w,
    const float* __restrict__ bias, float* __restrict__ out) {
  int b = blockIdx.x, ocg = blockIdx.y;  // grid (32, 8)
  __shared__ float img[61 * 61];
  __shared__ __align__(16) float wl[81][32];  // [k][oc]
  int t = threadIdx.x;
  for (int i = t; i < 61 * 61; i += 256) img[i] = x[b * 3721 + i];
  for (int i = t; i < 81 * 32; i += 256) {
    int k = i >> 5, oc = i & 31;
    wl[k][oc] = w[(ocg * 32 + oc) * 81 + k];
  }
  __syncthreads();
  int ocs = (t & 7) * 4;  // 8 subgroups * 4 oc
  int pg  = t >> 3;       // 32 position groups
  int oc0 = ocg * 32 + ocs;
  float b0 = bias[oc0 + 0], b1 = bias[oc0 + 1], b2 = bias[oc0 + 2],
        b3 = bias[oc0 + 3];
  for (int p = pg; p < 729; p += 32) {
    int oh = p / 27, ow = p - oh * 27;
    float a0 = 0.f, a1 = 0.f, a2 = 0.f, a3 = 0.f;
    const float* ib = &img[oh * 2 * 61 + ow * 2];
#pragma unroll
    for (int kh = 0; kh < 9; ++kh) {
#pragma unroll
      for (int kw = 0; kw < 9; ++kw) {
        float v = ib[kh * 61 + kw];
        const float4 wv =
            *reinterpret_cast<const float4*>(&wl[kh * 9 + kw][ocs]);
        a0 += v * wv.x; a1 += v * wv.y; a2 += v * wv.z; a3 += v * wv.w;
      }
    }
    out[((b * 256 + oc0 + 0) * 729) + p] = fmaxf(a0 + b0, 0.f);
    out[((b * 256 + oc0 + 1) * 729) + p] = fmaxf(a1 + b1, 0.f);
    out[((b * 256 + oc0 + 2) * 729) + p] = fmaxf(a2 + b2, 0.f);
    out[((b * 256 + oc0 + 3) * 729) + p] = fmaxf(a3 + b3, 0.f);
  }
}

// ---------- generic 256-in-ch conv, k9: used for conv1 and primary caps -----
// grid (32, 16); 256 threads; 16 oc per block; thread: 4 oc x PPT positions.
template <int IH, int IW, int OH, int OW, int S, int PPT, bool RELU>
__global__ __launch_bounds__(256) void convk(
    const float* __restrict__ in,    // [32][256][IH*IW]
    const float* __restrict__ wt,    // [(ic*81+k)*256 + oc]
    const float* __restrict__ bias,  // [256]
    float* __restrict__ out) {       // [32][256][OH*OW]
  constexpr int IHW  = IH * IW;
  constexpr int NPOS = OH * OW;
  constexpr int ICC  = 4;
  int b = blockIdx.x, ocg = blockIdx.y;
  __shared__ __align__(16) float inl[ICC * IHW];
  __shared__ __align__(16) float wl[ICC * 81 * 16];  // [ic*81+k][16 oc]
  int t    = threadIdx.x;
  int ocl4 = (t & 3) * 4;
  int pg   = t >> 2;  // 0..63
  int rowb[PPT];
#pragma unroll
  for (int j = 0; j < PPT; ++j) {
    int p  = pg * PPT + j;
    int pp = (p < NPOS) ? p : 0;  // clamp OOB positions to a safe address
    int oh = pp / OW, ow = pp - oh * OW;
    rowb[j] = oh * S * IW + ow * S;
  }
  float a0[PPT], a1[PPT], a2[PPT], a3[PPT];
#pragma unroll
  for (int j = 0; j < PPT; ++j) { a0[j] = a1[j] = a2[j] = a3[j] = 0.f; }

  for (int ic0 = 0; ic0 < 256; ic0 += ICC) {
    for (int i = t; i < ICC * IHW; i += 256)
      inl[i] = in[((b * 256 + ic0) * IHW) + i];
    for (int i = t; i < ICC * 81 * 16; i += 256) {
      int ick = i >> 4, ocl = i & 15;
      wl[i] = wt[(ic0 * 81 + ick) * 256 + ocg * 16 + ocl];
    }
    __syncthreads();
#pragma unroll
    for (int ic = 0; ic < ICC; ++ic) {
      for (int kh = 0; kh < 9; ++kh) {
        int ibase = ic * IHW + kh * IW;
        int wbase = (ic * 81 + kh * 9) * 16 + ocl4;
#pragma unroll
        for (int kw = 0; kw < 9; ++kw) {
          const float4 wv =
              *reinterpret_cast<const float4*>(&wl[wbase + kw * 16]);
#pragma unroll
          for (int j = 0; j < PPT; ++j) {
            float v = inl[ibase + rowb[j] + kw];
            a0[j] += v * wv.x; a1[j] += v * wv.y;
            a2[j] += v * wv.z; a3[j] += v * wv.w;
          }
        }
      }
    }
    __syncthreads();
  }
  int oc0 = ocg * 16 + ocl4;
  const float4 bv = *reinterpret_cast<const float4*>(&bias[oc0]);
#pragma unroll
  for (int j = 0; j < PPT; ++j) {
    int p = pg * PPT + j;
    if (p < NPOS) {
      float o0 = a0[j] + bv.x, o1 = a1[j] + bv.y, o2 = a2[j] + bv.z,
            o3 = a3[j] + bv.w;
      if (RELU) {
        o0 = fmaxf(o0, 0.f); o1 = fmaxf(o1, 0.f);
        o2 = fmaxf(o2, 0.f); o3 = fmaxf(o3, 0.f);
      }
      out[((b * 256 + oc0 + 0) * NPOS) + p] = o0;
      out[((b * 256 + oc0 + 1) * NPOS) + p] = o1;
      out[((b * 256 + oc0 + 2) * NPOS) + p] = o2;
      out[((b * 256 + oc0 + 3) * NPOS) + p] = o3;
    }
  }
}

// ---------- primary capsule squash: pp[32][256][36] -> caps[32][1152][8] ----
__global__ void prim_squash_kernel(const float* __restrict__ pp,
                                   float* __restrict__ caps) {
  int idx = blockIdx.x * blockDim.x + threadIdx.x;  // b*1152 + r
  if (idx >= NB * 1152) return;
  int b = idx / 1152, r = idx - b * 1152;
  int m = r / 36, s = r - m * 36;
  float tv[8];
  float sn = 0.f;
#pragma unroll
  for (int g = 0; g < 8; ++g) {
    tv[g] = pp[((b * 256 + g * 32 + m) * 36) + s];
    sn += tv[g] * tv[g];
  }
  float sc = sqrtf(sn) / (1.f + sn);
#pragma unroll
  for (int g = 0; g < 8; ++g) caps[idx * 8 + g] = tv[g] * sc;
}

// ---------- dynamic routing (3 iters). priors kept in registers. ------------
// grid (C, B); 512 threads. Thread t: o = t&15, rhi = t>>4 (0..31).
// pri[k] = priors[r = k*32+rhi][o].
template <int R, int CI>
__global__ __launch_bounds__(512) void routing_kernel(
    const float* __restrict__ x,   // [B][R][CI]
    const float* __restrict__ W,   // [C][R][CI][16]
    float* __restrict__ out) {     // [B][C][16]
  constexpr int NREG = R * 16 / 512;
  int c = blockIdx.x, b = blockIdx.y;
  int C = gridDim.x;
  extern __shared__ float rdyn[];
  float* lg = rdyn;      // [R] logits
  float* pr = rdyn + R;  // [R] unnormalized exp
  __shared__ float red[512];
  __shared__ float vsh[17];
  int t   = threadIdx.x;
  int o   = t & 15;
  int rhi = t >> 4;  // 0..31
  const float* xb = x + (size_t)b * R * CI;
  const float* Wc = W + (size_t)c * R * CI * 16;

  float pri[NREG];
#pragma unroll
  for (int k = 0; k < NREG; ++k) {
    int r = k * 32 + rhi;
    float s = 0.f;
#pragma unroll
    for (int i = 0; i < CI; ++i)
      s += xb[r * CI + i] * Wc[((size_t)r * CI + i) * 16 + o];
    pri[k] = s;
  }
  for (int r = t; r < R; r += 512) lg[r] = 0.f;
  __syncthreads();

  for (int it = 0; it < 3; ++it) {
    // softmax over r of lg -> pr (unnormalized) and denom
    float lm = -1e30f;
    for (int r = t; r < R; r += 512) lm = fmaxf(lm, lg[r]);
    red[t] = lm; __syncthreads();
    for (int s2 = 256; s2 > 0; s2 >>= 1) {
      if (t < s2) red[t] = fmaxf(red[t], red[t + s2]);
      __syncthreads();
    }
    float m = red[0]; __syncthreads();
    float ls = 0.f;
    for (int r = t; r < R; r += 512) {
      float e = expf(lg[r] - m);
      pr[r] = e;
      ls += e;
    }
    red[t] = ls; __syncthreads();
    for (int s2 = 256; s2 > 0; s2 >>= 1) {
      if (t < s2) red[t] += red[t + s2];
      __syncthreads();
    }
    float denom = red[0]; __syncthreads();
    // s[o] = (1/denom) * sum_r pr[r]*pri[r][o]
    float part = 0.f;
#pragma unroll
    for (int k = 0; k < NREG; ++k) part += pr[k * 32 + rhi] * pri[k];
    red[t] = part; __syncthreads();
    if (t < 16) {
      float sv = 0.f;
      for (int kk = 0; kk < 32; ++kk) sv += red[kk * 16 + t];
      vsh[t] = sv / denom;
    }
    __syncthreads();
    if (t == 0) {
      float sn = 0.f;
      for (int oo = 0; oo < 16; ++oo) sn += vsh[oo] * vsh[oo];
      vsh[16] = sqrtf(sn) / (1.f + sn);  // squash scale
    }
    __syncthreads();
    if (it < 2) {
      float vo = vsh[o] * vsh[16];  // outputs[o]
      // delta logit[r] = sum_o pri[r][o]*outputs[o] via 16-lane butterflies
#pragma unroll
      for (int k = 0; k < NREG; ++k) {
        float val = pri[k] * vo;
        val += __shfl_xor(val, 1);
        val += __shfl_xor(val, 2);
        val += __shfl_xor(val, 4);
        val += __shfl_xor(val, 8);
        if (o == 0) lg[k * 32 + rhi] += val;
      }
      __syncthreads();
    }
  }
  if (t < 16) out[((size_t)b * C + c) * 16 + t] = vsh[t] * vsh[16];
}

// ---------- classes: norms -> softmax -> argmax -> masked z -----------------
__global__ void classes_kernel(const float* __restrict__ v,
                               float* __restrict__ outc,
                               float* __restrict__ z) {
  int b = blockIdx.x;  // 32 blocks, 64 threads
  int t = threadIdx.x;
  __shared__ float nrm[10];
  __shared__ int amax;
  if (t < 10) {
    float sn = 0.f;
#pragma unroll
    for (int o = 0; o < 16; ++o) {
      float xv = v[(b * 10 + t) * 16 + o];
      sn += xv * xv;
    }
    nrm[t] = sqrtf(sn);
  }
  __syncthreads();
  if (t == 0) {
    float m = nrm[0];
    int am = 0;
    for (int c = 1; c < 10; ++c)
      if (nrm[c] > m) { m = nrm[c]; am = c; }  // first-max (jnp.argmax)
    float s = 0.f;
    float e[10];
    for (int c = 0; c < 10; ++c) { e[c] = expf(nrm[c] - m); s += e[c]; }
    for (int c = 0; c < 10; ++c) outc[b * 10 + c] = e[c] / s;
    amax = am;
  }
  __syncthreads();
  int am = amax;
  for (int i = t; i < 160; i += 64) {
    int c = i >> 4;
    z[b * 160 + i] = (c == am) ? v[(b * 10 + c) * 16 + (i & 15)] : 0.f;
  }
}

// ---------- decoder FC layer: out[32][N] = act(in[32][K] @ w[K][N] + b) -----
template <int K, bool RELU, bool SIG>
__global__ __launch_bounds__(256) void fc_kernel(
    const float* __restrict__ in, const float* __restrict__ w,
    const float* __restrict__ bias, float* __restrict__ out, int N) {
  int n  = blockIdx.x * 256 + threadIdx.x;
  int b0 = blockIdx.y * 8;
  extern __shared__ float finl[];  // [8][K]
  for (int idx = threadIdx.x; idx < 8 * K; idx += 256) {
    int bb = idx / K, k = idx - bb * K;
    finl[idx] = in[(b0 + bb) * K + k];
  }
  __syncthreads();
  float acc[8];
#pragma unroll
  for (int bb = 0; bb < 8; ++bb) acc[bb] = 0.f;
  for (int k = 0; k < K; ++k) {
    float wv = w[(size_t)k * N + n];
#pragma unroll
    for (int bb = 0; bb < 8; ++bb) acc[bb] += finl[bb * K + k] * wv;
  }
  float bv = bias[n];
#pragma unroll
  for (int bb = 0; bb < 8; ++bb) {
    float y = acc[bb] + bv;
    if (RELU) y = fmaxf(y, 0.f);
    if (SIG)  y = 1.f / (1.f + expf(-y));
    out[(size_t)(b0 + bb) * N + n] = y;
  }
}

// ---------------------------------------------------------------------------
extern "C" void kernel_launch(void* const* d_in, const int* in_sizes, int n_in,
                              void* d_out, int out_size, void* d_ws,
                              size_t ws_size, hipStream_t stream) {
  const float* x       = (const float*)d_in[0];
  const float* conv0_w = (const float*)d_in[1];
  const float* conv0_b = (const float*)d_in[2];
  const float* conv1_w = (const float*)d_in[3];
  const float* conv1_b = (const float*)d_in[4];
  const float* prim_w  = (const float*)d_in[5];
  const float* prim_b  = (const float*)d_in[6];
  const float* W1      = (const float*)d_in[7];
  const float* W2      = (const float*)d_in[8];
  const float* dec_w1  = (const float*)d_in[9];
  const float* dec_b1  = (const float*)d_in[10];
  const float* dec_w2  = (const float*)d_in[11];
  const float* dec_b2  = (const float*)d_in[12];
  const float* dec_w3  = (const float*)d_in[13];
  const float* dec_b3  = (const float*)d_in[14];
  float* out = (float*)d_out;

  float* ws   = (float*)d_ws;
  float* w1t  = ws;                   // 5,308,416
  float* wpt  = w1t + 5308416;        // 5,308,416
  float* h0   = wpt + 5308416;        // 5,971,968  [32][256][27*27]
  float* h1   = h0 + 5971968;         // 2,957,312  [32][256][19*19]
  float* pp   = h1 + 2957312;         //   294,912  [32][256][36]
  float* caps = pp + 294912;          //   294,912  [32][1152][8]
  float* u    = caps + 294912;        //    32,768  [32][64][16]
  float* vc   = u + 32768;            //     5,120  [32][10][16]
  float* z    = vc + 5120;            //     5,120  [32][160]
  float* d1   = z + 5120;             //    32,768  [32][1024]
  float* d2   = d1 + 32768;           //    65,536  [32][2048]

  transpose_w_kernel<<<2048, 256, 0, stream>>>(conv1_w, w1t, 256 * 256 * 81);
  transpose_w_kernel<<<2048, 256, 0, stream>>>(prim_w, wpt, 256 * 256 * 81);

  conv0_kernel<<<dim3(NB, 8), 256, 0, stream>>>(x, conv0_w, conv0_b, h0);

  // conv1: 27x27 -> 19x19, s1, relu. PPT=6 (64 pgroups * 6 = 384 >= 361).
  convk<27, 27, 19, 19, 1, 6, true>
      <<<dim3(NB, 16), 256, 0, stream>>>(h0, w1t, conv1_b, h1);

  // primary caps: 19x19 -> 6x6, s2, no relu. PPT=1 (64 >= 36).
  convk<19, 19, 6, 6, 2, 1, false>
      <<<dim3(NB, 16), 256, 0, stream>>>(h1, wpt, prim_b, pp);

  prim_squash_kernel<<<(NB * 1152 + 255) / 256, 256, 0, stream>>>(pp, caps);

  routing_kernel<1152, 8>
      <<<dim3(64, NB), 512, 2 * 1152 * sizeof(float), stream>>>(caps, W1, u);
  routing_kernel<64, 16>
      <<<dim3(10, NB), 512, 2 * 64 * sizeof(float), stream>>>(u, W2, vc);

  classes_kernel<<<NB, 64, 0, stream>>>(vc, out, z);

  fc_kernel<160, true, false>
      <<<dim3(4, 4), 256, 8 * 160 * sizeof(float), stream>>>(z, dec_w1, dec_b1,
                                                             d1, 1024);
  fc_kernel<1024, true, false>
      <<<dim3(8, 4), 256, 8 * 1024 * sizeof(float), stream>>>(d1, dec_w2,
                                                              dec_b2, d2, 2048);
  fc_kernel<2048, false, true>
      <<<dim3(16, 4), 256, 8 * 2048 * sizeof(float), stream>>>(
          d2, dec_w3, dec_b3, out + 320, 4096);
}

// Round 2
// 4863.040 us; speedup vs baseline: 1.4853x; 1.4853x over previous
//
#include <hip/hip_runtime.h>
#include <hip/hip_bf16.h>
#include <math.h>

// ---------------------------------------------------------------------------
// CapsuleNet forward, fp32. Round 2: register-window direct convs.
// conv1: thread = 4 oc x 4 consecutive ow (aligned b128 windows, padded rows)
// prim : thread = 4 oc x full 6-wide output row, 16-way ic-split partials
// ---------------------------------------------------------------------------

#define NB 32  // batch

// ---------- weight transpose: w[oc][ic][9][9] -> wt[(ic*81+k)*256 + oc] -----
__global__ void transpose_w_kernel(const float* __restrict__ w,
                                   float* __restrict__ wt, int n) {
  for (int idx = blockIdx.x * blockDim.x + threadIdx.x; idx < n;
       idx += gridDim.x * blockDim.x) {
    int oc  = idx / (256 * 81);
    int rem = idx - oc * (256 * 81);   // ic*81 + k
    wt[rem * 256 + oc] = w[idx];
  }
}

// ---------- conv0: x[32][1][61][61] -> h0[32][256][27][28pad], k9 s2, relu --
__global__ __launch_bounds__(256) void conv0_kernel(
    const float* __restrict__ x, const float* __restrict__ w,
    const float* __restrict__ bias, float* __restrict__ out) {
  int b = blockIdx.x, ocg = blockIdx.y;  // grid (32, 8)
  __shared__ float img[61 * 61];
  __shared__ __align__(16) float wl[81][32];  // [k][oc]
  int t = threadIdx.x;
  for (int i = t; i < 61 * 61; i += 256) img[i] = x[b * 3721 + i];
  for (int i = t; i < 81 * 32; i += 256) {
    int k = i >> 5, oc = i & 31;
    wl[k][oc] = w[(ocg * 32 + oc) * 81 + k];
  }
  __syncthreads();
  int ocs = (t & 7) * 4;  // 8 subgroups * 4 oc
  int pg  = t >> 3;       // 32 position groups
  int oc0 = ocg * 32 + ocs;
  float b0 = bias[oc0 + 0], b1 = bias[oc0 + 1], b2 = bias[oc0 + 2],
        b3 = bias[oc0 + 3];
  for (int p = pg; p < 729; p += 32) {
    int oh = p / 27, ow = p - oh * 27;
    float a0 = 0.f, a1 = 0.f, a2 = 0.f, a3 = 0.f;
    const float* ib = &img[oh * 2 * 61 + ow * 2];
#pragma unroll
    for (int kh = 0; kh < 9; ++kh) {
#pragma unroll
      for (int kw = 0; kw < 9; ++kw) {
        float v = ib[kh * 61 + kw];
        const float4 wv =
            *reinterpret_cast<const float4*>(&wl[kh * 9 + kw][ocs]);
        a0 += v * wv.x; a1 += v * wv.y; a2 += v * wv.z; a3 += v * wv.w;
      }
    }
    int po = oh * 28 + ow;  // padded row stride 28
    out[((b * 256 + oc0 + 0) * 756) + po] = fmaxf(a0 + b0, 0.f);
    out[((b * 256 + oc0 + 1) * 756) + po] = fmaxf(a1 + b1, 0.f);
    out[((b * 256 + oc0 + 2) * 756) + po] = fmaxf(a2 + b2, 0.f);
    out[((b * 256 + oc0 + 3) * 756) + po] = fmaxf(a3 + b3, 0.f);
  }
}

// ---------- conv1: h0[32][256][27*28] -> h1[32][256][19*20], k9 s1, relu ----
// grid (32, 16); 384 threads. Thread: 4 oc x 4 consecutive ow in one row.
// pg = t>>2 (0..95): oh = pg/5, owg = pg%5, ow0 = owg*4 (owg 4 -> 3 valid).
__global__ __launch_bounds__(384) void conv1k(
    const float* __restrict__ in,    // [32][256][756]
    const float* __restrict__ wt,    // [(ic*81+k)*256 + oc]
    const float* __restrict__ bias,  // [256]
    float* __restrict__ out) {       // [32][256][380]
  constexpr int IHWP = 27 * 28;  // 756
  int b = blockIdx.x, ocg = blockIdx.y;
  __shared__ __align__(16) float inl[4 * IHWP];    // 12096 B
  __shared__ __align__(16) float wl[4 * 81 * 16];  // 20736 B
  int t    = threadIdx.x;
  int ocl4 = (t & 3) * 4;
  int pg   = t >> 2;           // 0..95
  int oh   = pg / 5;
  int owg  = pg - oh * 5;
  int ow0  = owg * 4;
  bool valid = (pg < 95);
  int ohc  = valid ? oh : 0;
  int npos = (owg == 4) ? 3 : 4;
  float acc[4][4];
#pragma unroll
  for (int j = 0; j < 4; ++j)
#pragma unroll
    for (int q = 0; q < 4; ++q) acc[j][q] = 0.f;

  const float* gin = in + (size_t)(b * 256) * IHWP;
  for (int ic0 = 0; ic0 < 256; ic0 += 4) {
    const float4* src = reinterpret_cast<const float4*>(gin + ic0 * IHWP);
    float4* dst = reinterpret_cast<float4*>(inl);
    for (int i = t; i < 756; i += 384) dst[i] = src[i];
    for (int i = t; i < 5184; i += 384) {
      int ick = i >> 4, ocl = i & 15;
      wl[i] = wt[(ic0 * 81 + ick) * 256 + ocg * 16 + ocl];
    }
    __syncthreads();
#pragma unroll
    for (int ic = 0; ic < 4; ++ic) {
      for (int kh = 0; kh < 9; ++kh) {
        float win[12];
        const float4* wsrc = reinterpret_cast<const float4*>(
            &inl[ic * IHWP + (ohc + kh) * 28 + ow0]);
        *reinterpret_cast<float4*>(&win[0]) = wsrc[0];
        *reinterpret_cast<float4*>(&win[4]) = wsrc[1];
        *reinterpret_cast<float4*>(&win[8]) = wsrc[2];
        const float* wbase = &wl[(ic * 81 + kh * 9) * 16 + ocl4];
#pragma unroll
        for (int kw = 0; kw < 9; ++kw) {
          const float4 wv =
              *reinterpret_cast<const float4*>(&wbase[kw * 16]);
#pragma unroll
          for (int j = 0; j < 4; ++j) {
            float v = win[j + kw];
            acc[j][0] += v * wv.x; acc[j][1] += v * wv.y;
            acc[j][2] += v * wv.z; acc[j][3] += v * wv.w;
          }
        }
      }
    }
    __syncthreads();
  }
  if (valid) {
    int oc0 = ocg * 16 + ocl4;
    const float4 bv = *reinterpret_cast<const float4*>(&bias[oc0]);
    float bb[4] = {bv.x, bv.y, bv.z, bv.w};
#pragma unroll
    for (int q = 0; q < 4; ++q) {
      for (int j = 0; j < npos; ++j) {
        out[((size_t)(b * 256 + oc0 + q)) * 380 + oh * 20 + ow0 + j] =
            fmaxf(acc[j][q] + bb[q], 0.f);
      }
    }
  }
}

// ---------- prim conv: h1[32][256][19*20] -> part[16][32][256][36], k9 s2 ---
// grid (32, 16 ic-groups); 384 threads: ocl4=(t&63)*4 (256 oc), row=t>>6 (6).
__global__ __launch_bounds__(384) void primk(
    const float* __restrict__ in,   // [32][256][380]
    const float* __restrict__ wt,   // [(ic*81+k)*256 + oc]
    float* __restrict__ part) {     // [16][32][256][36]
  constexpr int IHWP = 380;
  int b = blockIdx.x, icg = blockIdx.y;
  __shared__ __align__(16) float inl[4 * IHWP];  // 6080 B
  int t    = threadIdx.x;
  int ocl4 = (t & 63) * 4;
  int row  = t >> 6;  // 0..5
  float acc[6][4];
#pragma unroll
  for (int j = 0; j < 6; ++j)
#pragma unroll
    for (int q = 0; q < 4; ++q) acc[j][q] = 0.f;

  const float* gin = in + (size_t)(b * 256 + icg * 16) * IHWP;
  for (int c = 0; c < 4; ++c) {  // 4 chunks of 4 ic
    const float4* src = reinterpret_cast<const float4*>(gin + c * 4 * IHWP);
    float4* dst = reinterpret_cast<float4*>(inl);
    for (int i = t; i < 380; i += 384) dst[i] = src[i];
    __syncthreads();
#pragma unroll
    for (int ic = 0; ic < 4; ++ic) {
      for (int kh = 0; kh < 9; ++kh) {
        float win[20];
        const float4* wsrc = reinterpret_cast<const float4*>(
            &inl[ic * IHWP + (2 * row + kh) * 20]);
#pragma unroll
        for (int q = 0; q < 5; ++q)
          *reinterpret_cast<float4*>(&win[q * 4]) = wsrc[q];
        const float* wb =
            &wt[(size_t)(((icg * 16 + c * 4 + ic) * 81 + kh * 9)) * 256 +
                ocl4];
#pragma unroll
        for (int kw = 0; kw < 9; ++kw) {
          const float4 wv = *reinterpret_cast<const float4*>(&wb[kw * 256]);
#pragma unroll
          for (int j = 0; j < 6; ++j) {
            float v = win[2 * j + kw];
            acc[j][0] += v * wv.x; acc[j][1] += v * wv.y;
            acc[j][2] += v * wv.z; acc[j][3] += v * wv.w;
          }
        }
      }
    }
    __syncthreads();
  }
#pragma unroll
  for (int q = 0; q < 4; ++q)
    for (int j = 0; j < 6; ++j)
      part[((size_t)(icg * 32 + b) * 256 + ocl4 + q) * 36 + row * 6 + j] =
          acc[j][q];
}

// ---------- prim reduce + bias + squash: part -> caps[32][1152][8] ----------
__global__ void prim_squash_kernel(const float* __restrict__ part,
                                   const float* __restrict__ bias,
                                   float* __restrict__ caps) {
  int idx = blockIdx.x * blockDim.x + threadIdx.x;  // b*1152 + r
  if (idx >= NB * 1152) return;
  int b = idx / 1152, r = idx - b * 1152;
  int m = r / 36, s = r - m * 36;
  float tv[8];
  float sn = 0.f;
#pragma unroll
  for (int g = 0; g < 8; ++g) {
    int oc = g * 32 + m;
    float v = bias[oc];
    for (int sp = 0; sp < 16; ++sp)
      v += part[((size_t)(sp * 32 + b) * 256 + oc) * 36 + s];
    tv[g] = v;
    sn += v * v;
  }
  float sc = sqrtf(sn) / (1.f + sn);
#pragma unroll
  for (int g = 0; g < 8; ++g) caps[idx * 8 + g] = tv[g] * sc;
}

// ---------- dynamic routing (3 iters). priors kept in registers. ------------
template <int R, int CI>
__global__ __launch_bounds__(512) void routing_kernel(
    const float* __restrict__ x,   // [B][R][CI]
    const float* __restrict__ W,   // [C][R][CI][16]
    float* __restrict__ out) {     // [B][C][16]
  constexpr int NREG = R * 16 / 512;
  int c = blockIdx.x, b = blockIdx.y;
  int C = gridDim.x;
  extern __shared__ float rdyn[];
  float* lg = rdyn;      // [R] logits
  float* pr = rdyn + R;  // [R] unnormalized exp
  __shared__ float red[512];
  __shared__ float vsh[17];
  int t   = threadIdx.x;
  int o   = t & 15;
  int rhi = t >> 4;  // 0..31
  const float* xb = x + (size_t)b * R * CI;
  const float* Wc = W + (size_t)c * R * CI * 16;

  float pri[NREG];
#pragma unroll
  for (int k = 0; k < NREG; ++k) {
    int r = k * 32 + rhi;
    float s = 0.f;
#pragma unroll
    for (int i = 0; i < CI; ++i)
      s += xb[r * CI + i] * Wc[((size_t)r * CI + i) * 16 + o];
    pri[k] = s;
  }
  for (int r = t; r < R; r += 512) lg[r] = 0.f;
  __syncthreads();

  for (int it = 0; it < 3; ++it) {
    float lm = -1e30f;
    for (int r = t; r < R; r += 512) lm = fmaxf(lm, lg[r]);
    red[t] = lm; __syncthreads();
    for (int s2 = 256; s2 > 0; s2 >>= 1) {
      if (t < s2) red[t] = fmaxf(red[t], red[t + s2]);
      __syncthreads();
    }
    float m = red[0]; __syncthreads();
    float ls = 0.f;
    for (int r = t; r < R; r += 512) {
      float e = expf(lg[r] - m);
      pr[r] = e;
      ls += e;
    }
    red[t] = ls; __syncthreads();
    for (int s2 = 256; s2 > 0; s2 >>= 1) {
      if (t < s2) red[t] += red[t + s2];
      __syncthreads();
    }
    float denom = red[0]; __syncthreads();
    float part = 0.f;
#pragma unroll
    for (int k = 0; k < NREG; ++k) part += pr[k * 32 + rhi] * pri[k];
    red[t] = part; __syncthreads();
    if (t < 16) {
      float sv = 0.f;
      for (int kk = 0; kk < 32; ++kk) sv += red[kk * 16 + t];
      vsh[t] = sv / denom;
    }
    __syncthreads();
    if (t == 0) {
      float sn = 0.f;
      for (int oo = 0; oo < 16; ++oo) sn += vsh[oo] * vsh[oo];
      vsh[16] = sqrtf(sn) / (1.f + sn);
    }
    __syncthreads();
    if (it < 2) {
      float vo = vsh[o] * vsh[16];
#pragma unroll
      for (int k = 0; k < NREG; ++k) {
        float val = pri[k] * vo;
        val += __shfl_xor(val, 1);
        val += __shfl_xor(val, 2);
        val += __shfl_xor(val, 4);
        val += __shfl_xor(val, 8);
        if (o == 0) lg[k * 32 + rhi] += val;
      }
      __syncthreads();
    }
  }
  if (t < 16) out[((size_t)b * C + c) * 16 + t] = vsh[t] * vsh[16];
}

// ---------- classes: norms -> softmax -> argmax -> masked z -----------------
__global__ void classes_kernel(const float* __restrict__ v,
                               float* __restrict__ outc,
                               float* __restrict__ z) {
  int b = blockIdx.x;  // 32 blocks, 64 threads
  int t = threadIdx.x;
  __shared__ float nrm[10];
  __shared__ int amax;
  if (t < 10) {
    float sn = 0.f;
#pragma unroll
    for (int o = 0; o < 16; ++o) {
      float xv = v[(b * 10 + t) * 16 + o];
      sn += xv * xv;
    }
    nrm[t] = sqrtf(sn);
  }
  __syncthreads();
  if (t == 0) {
    float m = nrm[0];
    int am = 0;
    for (int c = 1; c < 10; ++c)
      if (nrm[c] > m) { m = nrm[c]; am = c; }  // first-max (jnp.argmax)
    float s = 0.f;
    float e[10];
    for (int c = 0; c < 10; ++c) { e[c] = expf(nrm[c] - m); s += e[c]; }
    for (int c = 0; c < 10; ++c) outc[b * 10 + c] = e[c] / s;
    amax = am;
  }
  __syncthreads();
  int am = amax;
  for (int i = t; i < 160; i += 64) {
    int c = i >> 4;
    z[b * 160 + i] = (c == am) ? v[(b * 10 + c) * 16 + (i & 15)] : 0.f;
  }
}

// ---------- decoder FC layer: out[32][N] = act(in[32][K] @ w[K][N] + b) -----
template <int K, bool RELU, bool SIG>
__global__ __launch_bounds__(256) void fc_kernel(
    const float* __restrict__ in, const float* __restrict__ w,
    const float* __restrict__ bias, float* __restrict__ out, int N) {
  int n  = blockIdx.x * 256 + threadIdx.x;
  int b0 = blockIdx.y * 8;
  extern __shared__ float finl[];  // [8][K]
  for (int idx = threadIdx.x; idx < 8 * K; idx += 256) {
    int bb = idx / K, k = idx - bb * K;
    finl[idx] = in[(b0 + bb) * K + k];
  }
  __syncthreads();
  float acc[8];
#pragma unroll
  for (int bb = 0; bb < 8; ++bb) acc[bb] = 0.f;
  for (int k = 0; k < K; ++k) {
    float wv = w[(size_t)k * N + n];
#pragma unroll
    for (int bb = 0; bb < 8; ++bb) acc[bb] += finl[bb * K + k] * wv;
  }
  float bv = bias[n];
#pragma unroll
  for (int bb = 0; bb < 8; ++bb) {
    float y = acc[bb] + bv;
    if (RELU) y = fmaxf(y, 0.f);
    if (SIG)  y = 1.f / (1.f + expf(-y));
    out[(size_t)(b0 + bb) * N + n] = y;
  }
}

// ---------------------------------------------------------------------------
extern "C" void kernel_launch(void* const* d_in, const int* in_sizes, int n_in,
                              void* d_out, int out_size, void* d_ws,
                              size_t ws_size, hipStream_t stream) {
  const float* x       = (const float*)d_in[0];
  const float* conv0_w = (const float*)d_in[1];
  const float* conv0_b = (const float*)d_in[2];
  const float* conv1_w = (const float*)d_in[3];
  const float* conv1_b = (const float*)d_in[4];
  const float* prim_w  = (const float*)d_in[5];
  const float* prim_b  = (const float*)d_in[6];
  const float* W1      = (const float*)d_in[7];
  const float* W2      = (const float*)d_in[8];
  const float* dec_w1  = (const float*)d_in[9];
  const float* dec_b1  = (const float*)d_in[10];
  const float* dec_w2  = (const float*)d_in[11];
  const float* dec_b2  = (const float*)d_in[12];
  const float* dec_w3  = (const float*)d_in[13];
  const float* dec_b3  = (const float*)d_in[14];
  float* out = (float*)d_out;

  float* ws   = (float*)d_ws;
  float* w1t  = ws;                   // 5,308,416
  float* wpt  = w1t + 5308416;        // 5,308,416
  float* h0   = wpt + 5308416;        // 6,193,152  [32][256][27*28]
  float* part = h0;                   // 4,718,592  [16][32][256][36] (alias)
  float* h1   = h0 + 6193152;         // 3,112,960  [32][256][19*20]
  float* caps = h1 + 3112960;         //   294,912  [32][1152][8]
  float* u    = caps + 294912;        //    32,768  [32][64][16]
  float* vc   = u + 32768;            //     5,120  [32][10][16]
  float* z    = vc + 5120;            //     5,120  [32][160]
  float* d1   = z + 5120;             //    32,768  [32][1024]
  float* d2   = d1 + 32768;           //    65,536  [32][2048]

  transpose_w_kernel<<<2048, 256, 0, stream>>>(conv1_w, w1t, 256 * 256 * 81);
  transpose_w_kernel<<<2048, 256, 0, stream>>>(prim_w, wpt, 256 * 256 * 81);

  conv0_kernel<<<dim3(NB, 8), 256, 0, stream>>>(x, conv0_w, conv0_b, h0);

  conv1k<<<dim3(NB, 16), 384, 0, stream>>>(h0, w1t, conv1_b, h1);

  // h0 dead from here; part aliases it.
  primk<<<dim3(NB, 16), 384, 0, stream>>>(h1, wpt, part);

  prim_squash_kernel<<<(NB * 1152 + 255) / 256, 256, 0, stream>>>(part, prim_b,
                                                                  caps);

  routing_kernel<1152, 8>
      <<<dim3(64, NB), 512, 2 * 1152 * sizeof(float), stream>>>(caps, W1, u);
  routing_kernel<64, 16>
      <<<dim3(10, NB), 512, 2 * 64 * sizeof(float), stream>>>(u, W2, vc);

  classes_kernel<<<NB, 64, 0, stream>>>(vc, out, z);

  fc_kernel<160, true, false>
      <<<dim3(4, 4), 256, 8 * 160 * sizeof(float), stream>>>(z, dec_w1, dec_b1,
                                                             d1, 1024);
  fc_kernel<1024, true, false>
      <<<dim3(8, 4), 256, 8 * 1024 * sizeof(float), stream>>>(d1, dec_w2,
                                                              dec_b2, d2, 2048);
  fc_kernel<2048, false, true>
      <<<dim3(16, 4), 256, 8 * 2048 * sizeof(float), stream>>>(
          d2, dec_w3, dec_b3, out + 320, 4096);
}

// Round 3
// 2532.934 us; speedup vs baseline: 2.8516x; 1.9199x over previous
//
#include <hip/hip_runtime.h>
#include <hip/hip_bf16.h>
#include <math.h>

// ---------------------------------------------------------------------------
// CapsuleNet forward, fp32. Round 3: occupancy (4 blocks/CU convs),
// split-K decoder FCs, sparse fc1, defensive routing, coalesced transpose.
// ---------------------------------------------------------------------------

#define NB 32  // batch

// ---------- weight transpose: w[oc][ic][9][9] -> wt[(ic*81+k)*256 + oc] -----
// Iterate over OUTPUT index -> coalesced writes; strided reads absorbed by L2.
__global__ void transpose_w_kernel(const float* __restrict__ w,
                                   float* __restrict__ wt, int n) {
  for (int j = blockIdx.x * blockDim.x + threadIdx.x; j < n;
       j += gridDim.x * blockDim.x) {
    int oc = j & 255, rem = j >> 8;  // j = rem*256 + oc
    wt[j] = w[oc * 20736 + rem];
  }
}

// ---------- conv0: x[32][1][61][61] -> h0[32][256][27][28pad], k9 s2, relu --
__global__ __launch_bounds__(256) void conv0_kernel(
    const float* __restrict__ x, const float* __restrict__ w,
    const float* __restrict__ bias, float* __restrict__ out) {
  int b = blockIdx.x, ocg = blockIdx.y, z = blockIdx.z;  // grid (32, 8, 2)
  __shared__ float img[61 * 61];
  __shared__ __align__(16) float wl[81][32];  // [k][oc]
  int t = threadIdx.x;
  for (int i = t; i < 61 * 61; i += 256) img[i] = x[b * 3721 + i];
  for (int i = t; i < 81 * 32; i += 256) {
    int k = i >> 5, oc = i & 31;
    wl[k][oc] = w[(ocg * 32 + oc) * 81 + k];
  }
  __syncthreads();
  int ocs = (t & 7) * 4;  // 8 subgroups * 4 oc
  int pg  = t >> 3;       // 32 position groups
  int oc0 = ocg * 32 + ocs;
  float b0 = bias[oc0 + 0], b1 = bias[oc0 + 1], b2 = bias[oc0 + 2],
        b3 = bias[oc0 + 3];
  for (int p = pg + z * 32; p < 729; p += 64) {
    int oh = p / 27, ow = p - oh * 27;
    float a0 = 0.f, a1 = 0.f, a2 = 0.f, a3 = 0.f;
    const float* ib = &img[oh * 2 * 61 + ow * 2];
#pragma unroll
    for (int kh = 0; kh < 9; ++kh) {
#pragma unroll
      for (int kw = 0; kw < 9; ++kw) {
        float v = ib[kh * 61 + kw];
        const float4 wv =
            *reinterpret_cast<const float4*>(&wl[kh * 9 + kw][ocs]);
        a0 += v * wv.x; a1 += v * wv.y; a2 += v * wv.z; a3 += v * wv.w;
      }
    }
    int po = oh * 28 + ow;  // padded row stride 28
    out[((b * 256 + oc0 + 0) * 756) + po] = fmaxf(a0 + b0, 0.f);
    out[((b * 256 + oc0 + 1) * 756) + po] = fmaxf(a1 + b1, 0.f);
    out[((b * 256 + oc0 + 2) * 756) + po] = fmaxf(a2 + b2, 0.f);
    out[((b * 256 + oc0 + 3) * 756) + po] = fmaxf(a3 + b3, 0.f);
  }
}

// ---------- conv1: h0[32][256][27*28] -> h1[32][256][19*20], k9 s1, relu ----
// grid (32, 16, 2); 192 threads. Thread: 4 oc x 4 consecutive ow in one row.
// z picks pgroup half: pg = z*48 + (t>>2); 95 valid groups total.
__global__ __launch_bounds__(192) void conv1k(
    const float* __restrict__ in,    // [32][256][756]
    const float* __restrict__ wt,    // [(ic*81+k)*256 + oc]
    const float* __restrict__ bias,  // [256]
    float* __restrict__ out) {       // [32][256][380]
  constexpr int IHWP = 27 * 28;  // 756
  int b = blockIdx.x, ocg = blockIdx.y, z = blockIdx.z;
  __shared__ __align__(16) float inl[4 * IHWP];    // 12096 B
  __shared__ __align__(16) float wl[4 * 81 * 16];  // 20736 B
  int t    = threadIdx.x;
  int ocl4 = (t & 3) * 4;
  int pg   = z * 48 + (t >> 2);  // 0..95
  int oh   = pg / 5;
  int owg  = pg - oh * 5;
  int ow0  = owg * 4;
  bool valid = (pg < 95);
  int ohc  = valid ? oh : 0;
  int npos = (owg == 4) ? 3 : 4;
  float acc[4][4];
#pragma unroll
  for (int j = 0; j < 4; ++j)
#pragma unroll
    for (int q = 0; q < 4; ++q) acc[j][q] = 0.f;

  const float* gin = in + (size_t)(b * 256) * IHWP;
  const float4* wt4 = reinterpret_cast<const float4*>(wt);
  for (int ic0 = 0; ic0 < 256; ic0 += 4) {
    const float4* src = reinterpret_cast<const float4*>(gin + ic0 * IHWP);
    float4* dst = reinterpret_cast<float4*>(inl);
    for (int i = t; i < 756; i += 192) dst[i] = src[i];
    float4* wdst = reinterpret_cast<float4*>(wl);
    for (int i = t; i < 1296; i += 192) {
      int ick = i >> 2, oclq = i & 3;
      wdst[i] = wt4[(ic0 * 81 + ick) * 64 + ocg * 4 + oclq];
    }
    __syncthreads();
#pragma unroll
    for (int ic = 0; ic < 4; ++ic) {
      for (int kh = 0; kh < 9; ++kh) {
        float win[12];
        const float4* wsrc = reinterpret_cast<const float4*>(
            &inl[ic * IHWP + (ohc + kh) * 28 + ow0]);
        *reinterpret_cast<float4*>(&win[0]) = wsrc[0];
        *reinterpret_cast<float4*>(&win[4]) = wsrc[1];
        *reinterpret_cast<float4*>(&win[8]) = wsrc[2];
        const float* wbase = &wl[(ic * 81 + kh * 9) * 16 + ocl4];
#pragma unroll
        for (int kw = 0; kw < 9; ++kw) {
          const float4 wv =
              *reinterpret_cast<const float4*>(&wbase[kw * 16]);
#pragma unroll
          for (int j = 0; j < 4; ++j) {
            float v = win[j + kw];
            acc[j][0] += v * wv.x; acc[j][1] += v * wv.y;
            acc[j][2] += v * wv.z; acc[j][3] += v * wv.w;
          }
        }
      }
    }
    __syncthreads();
  }
  if (valid) {
    int oc0 = ocg * 16 + ocl4;
    const float4 bv = *reinterpret_cast<const float4*>(&bias[oc0]);
    float bb[4] = {bv.x, bv.y, bv.z, bv.w};
#pragma unroll
    for (int q = 0; q < 4; ++q) {
      for (int j = 0; j < npos; ++j) {
        out[((size_t)(b * 256 + oc0 + q)) * 380 + oh * 20 + ow0 + j] =
            fmaxf(acc[j][q] + bb[q], 0.f);
      }
    }
  }
}

// ---------- prim conv: h1[32][256][19*20] -> part[16][32][256][36], k9 s2 ---
// grid (32, 16 ic-groups, 2 oc-half); 192 thr: ocl4=(t&31)*4+z*128, row=t>>5.
__global__ __launch_bounds__(192) void primk(
    const float* __restrict__ in,   // [32][256][380]
    const float* __restrict__ wt,   // [(ic*81+k)*256 + oc]
    float* __restrict__ part) {     // [16][32][256][36]
  constexpr int IHWP = 380;
  int b = blockIdx.x, icg = blockIdx.y, z = blockIdx.z;
  __shared__ __align__(16) float inl[4 * IHWP];  // 6080 B
  int t    = threadIdx.x;
  int ocl4 = (t & 31) * 4 + z * 128;
  int row  = t >> 5;  // 0..5
  float acc[6][4];
#pragma unroll
  for (int j = 0; j < 6; ++j)
#pragma unroll
    for (int q = 0; q < 4; ++q) acc[j][q] = 0.f;

  const float* gin = in + (size_t)(b * 256 + icg * 16) * IHWP;
  for (int c = 0; c < 4; ++c) {  // 4 chunks of 4 ic
    const float4* src = reinterpret_cast<const float4*>(gin + c * 4 * IHWP);
    float4* dst = reinterpret_cast<float4*>(inl);
    for (int i = t; i < 380; i += 192) dst[i] = src[i];
    __syncthreads();
#pragma unroll
    for (int ic = 0; ic < 4; ++ic) {
      for (int kh = 0; kh < 9; ++kh) {
        float win[20];
        const float4* wsrc = reinterpret_cast<const float4*>(
            &inl[ic * IHWP + (2 * row + kh) * 20]);
#pragma unroll
        for (int q = 0; q < 5; ++q)
          *reinterpret_cast<float4*>(&win[q * 4]) = wsrc[q];
        const float* wb =
            &wt[(size_t)(((icg * 16 + c * 4 + ic) * 81 + kh * 9)) * 256 +
                ocl4];
#pragma unroll
        for (int kw = 0; kw < 9; ++kw) {
          const float4 wv = *reinterpret_cast<const float4*>(&wb[kw * 256]);
#pragma unroll
          for (int j = 0; j < 6; ++j) {
            float v = win[2 * j + kw];
            acc[j][0] += v * wv.x; acc[j][1] += v * wv.y;
            acc[j][2] += v * wv.z; acc[j][3] += v * wv.w;
          }
        }
      }
    }
    __syncthreads();
  }
#pragma unroll
  for (int q = 0; q < 4; ++q)
    for (int j = 0; j < 6; ++j)
      part[((size_t)(icg * 32 + b) * 256 + ocl4 + q) * 36 + row * 6 + j] =
          acc[j][q];
}

// ---------- prim reduce + bias + squash: part -> caps[32][1152][8] ----------
__global__ void prim_squash_kernel(const float* __restrict__ part,
                                   const float* __restrict__ bias,
                                   float* __restrict__ caps) {
  int idx = blockIdx.x * blockDim.x + threadIdx.x;  // b*1152 + r
  if (idx >= NB * 1152) return;
  int b = idx / 1152, r = idx - b * 1152;
  int m = r / 36, s = r - m * 36;
  float tv[8];
  float sn = 0.f;
#pragma unroll
  for (int g = 0; g < 8; ++g) {
    int oc = g * 32 + m;
    float v = bias[oc];
#pragma unroll
    for (int sp = 0; sp < 16; ++sp)
      v += part[((size_t)(sp * 32 + b) * 256 + oc) * 36 + s];
    tv[g] = v;
    sn += v * v;
  }
  float sc = sqrtf(sn) / (1.f + sn);
#pragma unroll
  for (int g = 0; g < 8; ++g) caps[idx * 8 + g] = tv[g] * sc;
}

// ---------- dynamic routing (3 iters). priors in regs; x staged in LDS. -----
// grid (C, B); 512 threads. Thread t: o = t&15, rhi = t>>4 (0..31).
template <int R, int CI>
__global__ __launch_bounds__(512) void routing_kernel(
    const float* __restrict__ x,   // [B][R][CI]
    const float* __restrict__ W,   // [C][R][CI][16]
    float* __restrict__ out) {     // [B][C][16]
  constexpr int NREG = R * 16 / 512;
  int c = blockIdx.x, b = blockIdx.y;
  int C = gridDim.x;
  __shared__ float xls[R * CI];
  extern __shared__ float rdyn[];
  float* lg = rdyn;      // [R] logits
  float* pr = rdyn + R;  // [R] unnormalized exp
  __shared__ float redA[8], redB[8];
  __shared__ float sred[8][16];
  __shared__ float vsh[17];
  int t    = threadIdx.x;
  int o    = t & 15;
  int rhi  = t >> 4;   // 0..31
  int wid  = t >> 6;   // 0..7
  int lane = t & 63;
  const float* xb = x + (size_t)b * R * CI;
  const float* Wc = W + (size_t)c * R * CI * 16;

  for (int i = t; i < R * CI; i += 512) xls[i] = xb[i];
  for (int r = t; r < R; r += 512) lg[r] = 0.f;
  __syncthreads();

  float pri[NREG];
#pragma unroll 2
  for (int k = 0; k < NREG; ++k) {
    int r = k * 32 + rhi;
    float s = 0.f;
#pragma unroll
    for (int i = 0; i < CI; ++i)
      s += xls[r * CI + i] * Wc[((size_t)r * CI + i) * 16 + o];
    pri[k] = s;
  }

  for (int it = 0; it < 3; ++it) {
    // --- softmax over r of lg -> pr (unnormalized) + denom ---
    float lm = -1e30f;
    for (int r = t; r < R; r += 512) lm = fmaxf(lm, lg[r]);
#pragma unroll
    for (int s2 = 1; s2 <= 32; s2 <<= 1) lm = fmaxf(lm, __shfl_xor(lm, s2));
    if (lane == 0) redA[wid] = lm;
    __syncthreads();
    if (t == 0) {
      float m8 = redA[0];
#pragma unroll
      for (int w = 1; w < 8; ++w) m8 = fmaxf(m8, redA[w]);
      redA[0] = m8;
    }
    __syncthreads();
    float m = redA[0];
    float ls = 0.f;
    for (int r = t; r < R; r += 512) {
      float e = __expf(lg[r] - m);
      pr[r] = e;
      ls += e;
    }
#pragma unroll
    for (int s2 = 1; s2 <= 32; s2 <<= 1) ls += __shfl_xor(ls, s2);
    if (lane == 0) redB[wid] = ls;
    __syncthreads();  // also covers pr[] writes
    if (t == 0) {
      float s8 = 0.f;
#pragma unroll
      for (int w = 0; w < 8; ++w) s8 += redB[w];
      redB[0] = s8;
    }
    __syncthreads();
    float denom = redB[0];
    // --- s[o] = (1/denom) * sum_r pr[r]*pri[r][o] ---
    float part = 0.f;
#pragma unroll
    for (int k = 0; k < NREG; ++k) part += pr[k * 32 + rhi] * pri[k];
    part += __shfl_xor(part, 16);
    part += __shfl_xor(part, 32);
    if (lane < 16) sred[wid][lane] = part;
    __syncthreads();
    if (t < 16) {
      float sv = 0.f;
#pragma unroll
      for (int w = 0; w < 8; ++w) sv += sred[w][t];
      vsh[t] = sv / denom;
    }
    __syncthreads();
    if (t == 0) {
      float sn = 0.f;
#pragma unroll
      for (int oo = 0; oo < 16; ++oo) sn += vsh[oo] * vsh[oo];
      vsh[16] = sqrtf(sn) / (1.f + sn);  // squash scale
    }
    __syncthreads();
    if (it < 2) {
      float vo = vsh[o] * vsh[16];  // outputs[o]
#pragma unroll
      for (int k = 0; k < NREG; ++k) {
        float val = pri[k] * vo;
        val += __shfl_xor(val, 1);
        val += __shfl_xor(val, 2);
        val += __shfl_xor(val, 4);
        val += __shfl_xor(val, 8);
        if (o == 0) lg[k * 32 + rhi] += val;
      }
      __syncthreads();
    }
  }
  if (t < 16) out[((size_t)b * C + c) * 16 + t] = vsh[t] * vsh[16];
}

// ---------- classes: norms -> softmax -> argmax index -----------------------
__global__ void classes_kernel(const float* __restrict__ v,
                               float* __restrict__ outc,
                               int* __restrict__ amaxb) {
  int b = blockIdx.x;  // 32 blocks, 64 threads
  int t = threadIdx.x;
  __shared__ float nrm[10];
  if (t < 10) {
    float sn = 0.f;
#pragma unroll
    for (int o = 0; o < 16; ++o) {
      float xv = v[(b * 10 + t) * 16 + o];
      sn += xv * xv;
    }
    nrm[t] = sqrtf(sn);
  }
  __syncthreads();
  if (t == 0) {
    float m = nrm[0];
    int am = 0;
    for (int c = 1; c < 10; ++c)
      if (nrm[c] > m) { m = nrm[c]; am = c; }  // first-max (jnp.argmax)
    float s = 0.f;
    float e[10];
    for (int c = 0; c < 10; ++c) { e[c] = __expf(nrm[c] - m); s += e[c]; }
    for (int c = 0; c < 10; ++c) outc[b * 10 + c] = e[c] / s;
    amaxb[b] = am;
  }
}

// ---------- fc1 sparse: d1 = relu(z @ w1 + b1), z has 16 nonzeros/row -------
// grid (4, 4); 256 thr. n = bx*256+t, b-tile 8.
__global__ __launch_bounds__(256) void fc1s_kernel(
    const float* __restrict__ v, const int* __restrict__ amaxb,
    const float* __restrict__ w, const float* __restrict__ bias,
    float* __restrict__ out) {
  int n  = blockIdx.x * 256 + threadIdx.x;
  int b0 = blockIdx.y * 8;
  __shared__ float vls[8][16];
  __shared__ int ams[8];
  int t = threadIdx.x;
  if (t < 8) ams[t] = amaxb[b0 + t];
  __syncthreads();
  if (t < 128) {
    int bb = t >> 4, oo = t & 15;
    vls[bb][oo] = v[((b0 + bb) * 10 + ams[bb]) * 16 + oo];
  }
  __syncthreads();
  float bv = bias[n];
#pragma unroll
  for (int bb = 0; bb < 8; ++bb) {
    int row0 = ams[bb] * 16;
    float acc = bv;
#pragma unroll
    for (int oo = 0; oo < 16; ++oo)
      acc += vls[bb][oo] * w[(size_t)(row0 + oo) * 1024 + n];
    out[(size_t)(b0 + bb) * 1024 + n] = fmaxf(acc, 0.f);
  }
}

// ---------- split-K FC: partial over K-chunk -> pbuf[kz][32][N] -------------
template <int K, int KCH>
__global__ __launch_bounds__(256) void fcsplit_kernel(
    const float* __restrict__ in, const float* __restrict__ w,
    float* __restrict__ pbuf, int N) {
  int n  = blockIdx.x * 256 + threadIdx.x;
  int b0 = blockIdx.y * 8;
  int k0 = blockIdx.z * KCH;
  __shared__ __align__(16) float inl[KCH * 8];  // [k][bb]
  for (int idx = threadIdx.x; idx < 8 * KCH; idx += 256) {
    int bb = idx / KCH, k = idx - bb * KCH;
    inl[k * 8 + bb] = in[(size_t)(b0 + bb) * K + k0 + k];
  }
  __syncthreads();
  float acc[8];
#pragma unroll
  for (int bb = 0; bb < 8; ++bb) acc[bb] = 0.f;
  for (int k = 0; k < KCH; ++k) {
    float wv = w[(size_t)(k0 + k) * N + n];
    const float4 i0 = *reinterpret_cast<const float4*>(&inl[k * 8]);
    const float4 i1 = *reinterpret_cast<const float4*>(&inl[k * 8 + 4]);
    acc[0] += i0.x * wv; acc[1] += i0.y * wv;
    acc[2] += i0.z * wv; acc[3] += i0.w * wv;
    acc[4] += i1.x * wv; acc[5] += i1.y * wv;
    acc[6] += i1.z * wv; acc[7] += i1.w * wv;
  }
#pragma unroll
  for (int bb = 0; bb < 8; ++bb)
    pbuf[((size_t)blockIdx.z * 32 + b0 + bb) * N + n] = acc[bb];
}

// ---------- combine partials + bias + activation ----------------------------
template <int KS, bool RELU, bool SIG>
__global__ void fccomb_kernel(const float* __restrict__ pbuf,
                              const float* __restrict__ bias,
                              float* __restrict__ out, int N) {
  int idx = blockIdx.x * 256 + threadIdx.x;  // b*N + n
  if (idx >= 32 * N) return;
  int b = idx / N, n = idx - b * N;
  float a = bias[n];
#pragma unroll
  for (int kz = 0; kz < KS; ++kz) a += pbuf[((size_t)kz * 32 + b) * N + n];
  if (RELU) a = fmaxf(a, 0.f);
  if (SIG)  a = 1.f / (1.f + __expf(-a));
  out[idx] = a;
}

// ---------------------------------------------------------------------------
extern "C" void kernel_launch(void* const* d_in, const int* in_sizes, int n_in,
                              void* d_out, int out_size, void* d_ws,
                              size_t ws_size, hipStream_t stream) {
  const float* x       = (const float*)d_in[0];
  const float* conv0_w = (const float*)d_in[1];
  const float* conv0_b = (const float*)d_in[2];
  const float* conv1_w = (const float*)d_in[3];
  const float* conv1_b = (const float*)d_in[4];
  const float* prim_w  = (const float*)d_in[5];
  const float* prim_b  = (const float*)d_in[6];
  const float* W1      = (const float*)d_in[7];
  const float* W2      = (const float*)d_in[8];
  const float* dec_w1  = (const float*)d_in[9];
  const float* dec_b1  = (const float*)d_in[10];
  const float* dec_w2  = (const float*)d_in[11];
  const float* dec_b2  = (const float*)d_in[12];
  const float* dec_w3  = (const float*)d_in[13];
  const float* dec_b3  = (const float*)d_in[14];
  float* out = (float*)d_out;

  float* ws   = (float*)d_ws;
  float* w1t  = ws;                   // 5,308,416 (dead after conv1k)
  float* wpt  = w1t + 5308416;        // 5,308,416 (dead after primk)
  float* h0   = wpt + 5308416;        // 6,193,152  [32][256][27*28]
  float* part = h0;                   // 4,718,592  [16][32][256][36] (alias)
  float* h1   = h0 + 6193152;         // 3,112,960  [32][256][19*20]
  float* caps = h1 + 3112960;         //   294,912  [32][1152][8]
  float* u    = caps + 294912;        //    32,768  [32][64][16]
  float* vc   = u + 32768;            //     5,120  [32][10][16]
  int*   amaxb= (int*)(vc + 5120);    //        32
  float* d1   = vc + 5120 + 5120;     //    32,768  [32][1024]
  float* d2   = d1 + 32768;           //    65,536  [32][2048]
  float* pb2  = w1t;                  //   262,144  [4][32][2048] (alias w1t)
  float* pb3  = w1t + 262144;         // 1,048,576  [8][32][4096] (alias w1t)

  transpose_w_kernel<<<2048, 256, 0, stream>>>(conv1_w, w1t, 256 * 256 * 81);
  transpose_w_kernel<<<2048, 256, 0, stream>>>(prim_w, wpt, 256 * 256 * 81);

  conv0_kernel<<<dim3(NB, 8, 2), 256, 0, stream>>>(x, conv0_w, conv0_b, h0);

  conv1k<<<dim3(NB, 16, 2), 192, 0, stream>>>(h0, w1t, conv1_b, h1);

  // h0 dead from here; part aliases it.
  primk<<<dim3(NB, 16, 2), 192, 0, stream>>>(h1, wpt, part);

  prim_squash_kernel<<<(NB * 1152 + 255) / 256, 256, 0, stream>>>(part, prim_b,
                                                                  caps);

  routing_kernel<1152, 8>
      <<<dim3(64, NB), 512, 2 * 1152 * sizeof(float), stream>>>(caps, W1, u);
  routing_kernel<64, 16>
      <<<dim3(10, NB), 512, 2 * 64 * sizeof(float), stream>>>(u, W2, vc);

  classes_kernel<<<NB, 64, 0, stream>>>(vc, out, amaxb);

  // decoder (w1t dead -> pb2/pb3 alias it)
  fc1s_kernel<<<dim3(4, 4), 256, 0, stream>>>(vc, amaxb, dec_w1, dec_b1, d1);

  fcsplit_kernel<1024, 256>
      <<<dim3(8, 4, 4), 256, 0, stream>>>(d1, dec_w2, pb2, 2048);
  fccomb_kernel<4, true, false>
      <<<256, 256, 0, stream>>>(pb2, dec_b2, d2, 2048);

  fcsplit_kernel<2048, 256>
      <<<dim3(16, 4, 8), 256, 0, stream>>>(d2, dec_w3, pb3, 4096);
  fccomb_kernel<8, false, true>
      <<<512, 256, 0, stream>>>(pb3, dec_b3, out + 320, 4096);
}

// Round 4
// 609.370 us; speedup vs baseline: 11.8532x; 4.1566x over previous
//
#include <hip/hip_runtime.h>
#include <hip/hip_bf16.h>
#include <math.h>

// ---------------------------------------------------------------------------
// CapsuleNet forward. Round 4: conv1 + primary-caps conv as fp16 MFMA
// implicit GEMM (K = (kh,kw,ic)); activations flow pos-major [pos][ic] fp16.
// ---------------------------------------------------------------------------

#define NB 32  // batch

typedef _Float16 f16;
typedef f16 f16x4 __attribute__((ext_vector_type(4)));
typedef f16 f16x8 __attribute__((ext_vector_type(8)));
typedef float f32x4 __attribute__((ext_vector_type(4)));

// ---------- weight prep: w[oc][ic][81] fp32 -> wo[tap][oc][ic] f16 ----------
__global__ void wprep_kernel(const float* __restrict__ w,
                             f16* __restrict__ wo) {
  for (int j = blockIdx.x * blockDim.x + threadIdx.x; j < 81 * 256 * 256;
       j += gridDim.x * blockDim.x) {
    int tap = j >> 16, rem = j & 65535;
    int oc = rem >> 8, ic = rem & 255;
    wo[j] = (f16)w[(oc * 256 + ic) * 81 + tap];
  }
}

// ---------- conv0: x[32][1][61][61] -> h0f[32][756][256] f16, k9 s2, relu ---
// (27 rows x 28 padded cols, ic-fastest; col 27 of each row left unwritten —
//  only ever read by discarded garbage output columns)
__global__ __launch_bounds__(256) void conv0_kernel(
    const float* __restrict__ x, const float* __restrict__ w,
    const float* __restrict__ bias, f16* __restrict__ outf) {
  int b = blockIdx.x, ocg = blockIdx.y, z = blockIdx.z;  // grid (32, 8, 2)
  __shared__ float img[61 * 61];
  __shared__ __align__(16) float wl[81][32];  // [k][oc]
  int t = threadIdx.x;
  for (int i = t; i < 61 * 61; i += 256) img[i] = x[b * 3721 + i];
  for (int i = t; i < 81 * 32; i += 256) {
    int k = i >> 5, oc = i & 31;
    wl[k][oc] = w[(ocg * 32 + oc) * 81 + k];
  }
  __syncthreads();
  int ocs = (t & 7) * 4;  // 8 subgroups * 4 oc
  int pg  = t >> 3;       // 32 position groups
  int oc0 = ocg * 32 + ocs;
  float b0 = bias[oc0 + 0], b1 = bias[oc0 + 1], b2 = bias[oc0 + 2],
        b3 = bias[oc0 + 3];
  for (int p = pg + z * 32; p < 729; p += 64) {
    int oh = p / 27, ow = p - oh * 27;
    float a0 = 0.f, a1 = 0.f, a2 = 0.f, a3 = 0.f;
    const float* ib = &img[oh * 2 * 61 + ow * 2];
#pragma unroll
    for (int kh = 0; kh < 9; ++kh) {
#pragma unroll
      for (int kw = 0; kw < 9; ++kw) {
        float v = ib[kh * 61 + kw];
        const float4 wv =
            *reinterpret_cast<const float4*>(&wl[kh * 9 + kw][ocs]);
        a0 += v * wv.x; a1 += v * wv.y; a2 += v * wv.z; a3 += v * wv.w;
      }
    }
    int po = oh * 28 + ow;
    f16x4 hv;
    hv[0] = (f16)fmaxf(a0 + b0, 0.f);
    hv[1] = (f16)fmaxf(a1 + b1, 0.f);
    hv[2] = (f16)fmaxf(a2 + b2, 0.f);
    hv[3] = (f16)fmaxf(a3 + b3, 0.f);
    *(f16x4*)&outf[((size_t)b * 756 + po) * 256 + oc0] = hv;
  }
}

// ---------- conv1 MFMA: h0f[32][756][256] -> part1[4][32][384][256] f16 -----
// grid (32 b, 4 ocg, 4 ksp); 256 thr = 4 waves.
// Block tile: 64 oc x 384 pos (n = oh*20+ow, oh<=19; n>=380 & ow==19 garbage),
// K = 64 ic (2 chunks of 32) x 81 taps. Wave: 4 Mfrag x 6 Nfrag, 24 MFMA/tap.
__global__ __launch_bounds__(256) void conv1_mfma(
    const f16* __restrict__ xin,  // [32][756][256]
    const f16* __restrict__ wA,   // [81][256][256]
    f16* __restrict__ part) {     // [4][32][384][256]
  int b = blockIdx.x, ocg = blockIdx.y, ksp = blockIdx.z;
  __shared__ __align__(16) f16 blds[784 * 40];  // [pos 28x28][40 pad]
  __shared__ __align__(16) f16 alds[64 * 40];   // [oc][40 pad]
  int t = threadIdx.x;
  int w = t >> 6, lane = t & 63, kg = lane >> 4, ln = lane & 15;
  int pbB[6];
#pragma unroll
  for (int nf = 0; nf < 6; ++nf) {
    int n = w * 96 + nf * 16 + ln;  // [0,384)
    int oh = n / 20, ow = n - oh * 20;
    pbB[nf] = ((oh * 28 + ow) * 40 + kg * 8) * 2;  // byte offset in blds
  }
  int aoffB = (ln * 40 + kg * 8) * 2;
  f32x4 acc[4][6];
#pragma unroll
  for (int m = 0; m < 4; ++m)
#pragma unroll
    for (int nf = 0; nf < 6; ++nf) acc[m][nf] = (f32x4){0.f, 0.f, 0.f, 0.f};

  const f16* xb = xin + (size_t)b * 756 * 256 + ksp * 64;
  for (int icc = 0; icc < 2; ++icc) {
    __syncthreads();  // prior compute done before blds overwrite
    // stage B: 784 rows x 32 ic (rows >= 756 duplicate row-28-back)
    for (int i = t; i < 784 * 4; i += 256) {
      int p28 = i >> 2, q = i & 3;
      int p = (p28 < 756) ? p28 : (p28 - 28);
      f16x8 v = *(const f16x8*)(xb + (size_t)p * 256 + icc * 32 + q * 8);
      *(f16x8*)&blds[p28 * 40 + q * 8] = v;
    }
    for (int tap = 0; tap < 81; ++tap) {
      __syncthreads();  // alds free to overwrite; blds staged (first iter)
      {  // stage A: 64 oc x 32 ic
        int oc = t >> 2, q = t & 3;
        f16x8 v = *(const f16x8*)(wA +
            ((size_t)tap * 256 + ocg * 64 + oc) * 256 + ksp * 64 +
            icc * 32 + q * 8);
        *(f16x8*)&alds[oc * 40 + q * 8] = v;
      }
      __syncthreads();
      int kh = tap / 9, kw = tap - kh * 9;
      int rowB = (kh * 28 + kw) * 80;  // byte shift for this tap
      f16x8 af[4];
#pragma unroll
      for (int m = 0; m < 4; ++m)
        af[m] = *(const f16x8*)((const char*)alds + m * (16 * 80) + aoffB);
      f16x8 bf[6];
#pragma unroll
      for (int nf = 0; nf < 6; ++nf)
        bf[nf] = *(const f16x8*)((const char*)blds + pbB[nf] + rowB);
#pragma unroll
      for (int m = 0; m < 4; ++m)
#pragma unroll
        for (int nf = 0; nf < 6; ++nf)
          acc[m][nf] = __builtin_amdgcn_mfma_f32_16x16x32_f16(
              af[m], bf[nf], acc[m][nf], 0, 0, 0);
    }
  }
  // store partials: part[ksp][b][n][oc] f16
  f16* pout = part + ((size_t)ksp * 32 + b) * 384 * 256 + ocg * 64;
#pragma unroll
  for (int m = 0; m < 4; ++m)
#pragma unroll
    for (int nf = 0; nf < 6; ++nf) {
      int n = w * 96 + nf * 16 + ln;
      int oc = m * 16 + kg * 4;
      f16x4 v;
#pragma unroll
      for (int j = 0; j < 4; ++j) v[j] = (f16)acc[m][nf][j];
      *(f16x4*)(pout + (size_t)n * 256 + oc) = v;
    }
}

// ---------- combine conv1 partials + bias + relu -> h1f[32][380][256] f16 ---
__global__ void comb1_kernel(const f16* __restrict__ part,
                             const float* __restrict__ bias,
                             f16* __restrict__ h1f) {
  int idx = blockIdx.x * 256 + threadIdx.x;  // (b, p, ocq) : 32*380*32
  if (idx >= 32 * 380 * 32) return;
  int ocq = idx & 31, rem = idx >> 5;
  int p = rem % 380, b = rem / 380;
  float a[8];
#pragma unroll
  for (int j = 0; j < 8; ++j) a[j] = bias[ocq * 8 + j];
#pragma unroll
  for (int k = 0; k < 4; ++k) {
    f16x8 v = *(const f16x8*)&part[(((size_t)k * 32 + b) * 384 + p) * 256 +
                                   ocq * 8];
#pragma unroll
    for (int j = 0; j < 8; ++j) a[j] += (float)v[j];
  }
  f16x8 o;
#pragma unroll
  for (int j = 0; j < 8; ++j) o[j] = (f16)fmaxf(a[j], 0.f);
  *(f16x8*)&h1f[((size_t)b * 380 + p) * 256 + ocq * 8] = o;
}

// ---------- prim conv MFMA: h1f -> part2[8][16][96][256] f32 ----------------
// grid (16 img-pair, 2 ocg, 8 ksp); 256 thr = 4 waves.
// Tile: 128 oc x 96 pos (2 img x [oh6<6 x ow6<8, ow6>=6 garbage]), 32 ic x 81.
__global__ __launch_bounds__(256) void prim_mfma(
    const f16* __restrict__ xin,  // h1f [32][380][256]
    const f16* __restrict__ wB,   // [81][256][256]
    float* __restrict__ part2) {  // [8][16][96][256]
  int ip = blockIdx.x, ocg = blockIdx.y, ksp = blockIdx.z;
  __shared__ __align__(16) f16 blds[768 * 40];  // [2 img][384 rows][40 pad]
  __shared__ __align__(16) f16 alds[128 * 40];
  int t = threadIdx.x;
  int w = t >> 6, lane = t & 63, kg = lane >> 4, ln = lane & 15;
  int mg = w >> 1, ng = w & 1;  // Mfrags mg*4..+4, Nfrags ng*3..+3
  int pb[3];
#pragma unroll
  for (int nf = 0; nf < 3; ++nf) {
    int rem = nf * 16 + ln;  // [0,48)
    int oh6 = rem >> 3, ow6 = rem & 7;
    pb[nf] = ng * 384 + oh6 * 40 + ow6 * 2;  // base pos index (kh=kw=0)
  }
  f32x4 acc[4][3];
#pragma unroll
  for (int m = 0; m < 4; ++m)
#pragma unroll
    for (int nf = 0; nf < 3; ++nf) acc[m][nf] = (f32x4){0.f, 0.f, 0.f, 0.f};

  // stage B once (32 ic): 768 rows (rows 380..383 per img duplicate)
  for (int i = t; i < 768 * 4; i += 256) {
    int pos = i >> 2, q = i & 3;
    int img = pos >= 384;
    int p = pos - img * 384;
    if (p >= 380) p -= 20;
    f16x8 v = *(const f16x8*)(xin +
        ((size_t)(ip * 2 + img) * 380 + p) * 256 + ksp * 32 + q * 8);
    *(f16x8*)&blds[pos * 40 + q * 8] = v;
  }
  for (int tap = 0; tap < 81; ++tap) {
    __syncthreads();
    for (int i = t; i < 512; i += 256) {  // stage A: 128 oc x 32 ic
      int oc = i >> 2, q = i & 3;
      f16x8 v = *(const f16x8*)(wB +
          ((size_t)tap * 256 + ocg * 128 + oc) * 256 + ksp * 32 + q * 8);
      *(f16x8*)&alds[oc * 40 + q * 8] = v;
    }
    __syncthreads();
    int kh = tap / 9, kw = tap - kh * 9;
    int shift = kh * 20 + kw;
    f16x8 af[4];
#pragma unroll
    for (int m = 0; m < 4; ++m)
      af[m] = *(const f16x8*)((const char*)alds +
                              (((mg * 4 + m) * 16 + ln) * 40 + kg * 8) * 2);
    f16x8 bf[3];
#pragma unroll
    for (int nf = 0; nf < 3; ++nf)
      bf[nf] = *(const f16x8*)((const char*)blds +
                               ((pb[nf] + shift) * 40 + kg * 8) * 2);
#pragma unroll
    for (int m = 0; m < 4; ++m)
#pragma unroll
      for (int nf = 0; nf < 3; ++nf)
        acc[m][nf] = __builtin_amdgcn_mfma_f32_16x16x32_f16(
            af[m], bf[nf], acc[m][nf], 0, 0, 0);
  }
  float* pout = part2 + ((size_t)ksp * 16 + ip) * 96 * 256 + ocg * 128;
#pragma unroll
  for (int m = 0; m < 4; ++m)
#pragma unroll
    for (int nf = 0; nf < 3; ++nf) {
      int n = ng * 48 + nf * 16 + ln;
      int oc = (mg * 4 + m) * 16 + kg * 4;
      *(f32x4*)(pout + (size_t)n * 256 + oc) = acc[m][nf];
    }
}

// ---------- sum prim ksplit partials: part2 -> sum2[16][96][256] ------------
__global__ void comb2_kernel(const float* __restrict__ part2,
                             float* __restrict__ sum2) {
  int idx = blockIdx.x * 256 + threadIdx.x;
  if (idx >= 16 * 96 * 256) return;
  float a = 0.f;
#pragma unroll
  for (int k = 0; k < 8; ++k) a += part2[(size_t)k * 393216 + idx];
  sum2[idx] = a;
}

// ---------- prim bias + squash: sum2 -> caps[32][1152][8] -------------------
__global__ void prim_squash_kernel(const float* __restrict__ sum2,
                                   const float* __restrict__ bias,
                                   float* __restrict__ caps) {
  int idx = blockIdx.x * blockDim.x + threadIdx.x;  // b*1152 + r
  if (idx >= NB * 1152) return;
  int b = idx / 1152, r = idx - b * 1152;
  int m = r / 36, s = r - m * 36;
  int oh6 = s / 6, ow6 = s - oh6 * 6;
  int n = (b & 1) * 48 + oh6 * 8 + ow6;
  const float* src = sum2 + ((size_t)(b >> 1) * 96 + n) * 256;
  float tv[8];
  float sn = 0.f;
#pragma unroll
  for (int g = 0; g < 8; ++g) {
    float v = src[g * 32 + m] + bias[g * 32 + m];
    tv[g] = v;
    sn += v * v;
  }
  float sc = sqrtf(sn) / (1.f + sn);
#pragma unroll
  for (int g = 0; g < 8; ++g) caps[idx * 8 + g] = tv[g] * sc;
}

// ---------- dynamic routing (3 iters). priors in regs; x staged in LDS. -----
template <int R, int CI>
__global__ __launch_bounds__(512) void routing_kernel(
    const float* __restrict__ x,   // [B][R][CI]
    const float* __restrict__ W,   // [C][R][CI][16]
    float* __restrict__ out) {     // [B][C][16]
  constexpr int NREG = R * 16 / 512;
  int c = blockIdx.x, b = blockIdx.y;
  int C = gridDim.x;
  __shared__ float xls[R * CI];
  extern __shared__ float rdyn[];
  float* lg = rdyn;      // [R] logits
  float* pr = rdyn + R;  // [R] unnormalized exp
  __shared__ float redA[8], redB[8];
  __shared__ float sred[8][16];
  __shared__ float vsh[17];
  int t    = threadIdx.x;
  int o    = t & 15;
  int rhi  = t >> 4;   // 0..31
  int wid  = t >> 6;   // 0..7
  int lane = t & 63;
  const float* xb = x + (size_t)b * R * CI;
  const float* Wc = W + (size_t)c * R * CI * 16;

  for (int i = t; i < R * CI; i += 512) xls[i] = xb[i];
  for (int r = t; r < R; r += 512) lg[r] = 0.f;
  __syncthreads();

  float pri[NREG];
#pragma unroll 2
  for (int k = 0; k < NREG; ++k) {
    int r = k * 32 + rhi;
    float s = 0.f;
#pragma unroll
    for (int i = 0; i < CI; ++i)
      s += xls[r * CI + i] * Wc[((size_t)r * CI + i) * 16 + o];
    pri[k] = s;
  }

  for (int it = 0; it < 3; ++it) {
    float lm = -1e30f;
    for (int r = t; r < R; r += 512) lm = fmaxf(lm, lg[r]);
#pragma unroll
    for (int s2 = 1; s2 <= 32; s2 <<= 1) lm = fmaxf(lm, __shfl_xor(lm, s2));
    if (lane == 0) redA[wid] = lm;
    __syncthreads();
    if (t == 0) {
      float m8 = redA[0];
#pragma unroll
      for (int w = 1; w < 8; ++w) m8 = fmaxf(m8, redA[w]);
      redA[0] = m8;
    }
    __syncthreads();
    float m = redA[0];
    float ls = 0.f;
    for (int r = t; r < R; r += 512) {
      float e = __expf(lg[r] - m);
      pr[r] = e;
      ls += e;
    }
#pragma unroll
    for (int s2 = 1; s2 <= 32; s2 <<= 1) ls += __shfl_xor(ls, s2);
    if (lane == 0) redB[wid] = ls;
    __syncthreads();
    if (t == 0) {
      float s8 = 0.f;
#pragma unroll
      for (int w = 0; w < 8; ++w) s8 += redB[w];
      redB[0] = s8;
    }
    __syncthreads();
    float denom = redB[0];
    float part = 0.f;
#pragma unroll
    for (int k = 0; k < NREG; ++k) part += pr[k * 32 + rhi] * pri[k];
    part += __shfl_xor(part, 16);
    part += __shfl_xor(part, 32);
    if (lane < 16) sred[wid][lane] = part;
    __syncthreads();
    if (t < 16) {
      float sv = 0.f;
#pragma unroll
      for (int w = 0; w < 8; ++w) sv += sred[w][t];
      vsh[t] = sv / denom;
    }
    __syncthreads();
    if (t == 0) {
      float sn = 0.f;
#pragma unroll
      for (int oo = 0; oo < 16; ++oo) sn += vsh[oo] * vsh[oo];
      vsh[16] = sqrtf(sn) / (1.f + sn);
    }
    __syncthreads();
    if (it < 2) {
      float vo = vsh[o] * vsh[16];
#pragma unroll
      for (int k = 0; k < NREG; ++k) {
        float val = pri[k] * vo;
        val += __shfl_xor(val, 1);
        val += __shfl_xor(val, 2);
        val += __shfl_xor(val, 4);
        val += __shfl_xor(val, 8);
        if (o == 0) lg[k * 32 + rhi] += val;
      }
      __syncthreads();
    }
  }
  if (t < 16) out[((size_t)b * C + c) * 16 + t] = vsh[t] * vsh[16];
}

// ---------- classes: norms -> softmax -> argmax index -----------------------
__global__ void classes_kernel(const float* __restrict__ v,
                               float* __restrict__ outc,
                               int* __restrict__ amaxb) {
  int b = blockIdx.x;  // 32 blocks, 64 threads
  int t = threadIdx.x;
  __shared__ float nrm[10];
  if (t < 10) {
    float sn = 0.f;
#pragma unroll
    for (int o = 0; o < 16; ++o) {
      float xv = v[(b * 10 + t) * 16 + o];
      sn += xv * xv;
    }
    nrm[t] = sqrtf(sn);
  }
  __syncthreads();
  if (t == 0) {
    float m = nrm[0];
    int am = 0;
    for (int c = 1; c < 10; ++c)
      if (nrm[c] > m) { m = nrm[c]; am = c; }  // first-max (jnp.argmax)
    float s = 0.f;
    float e[10];
    for (int c = 0; c < 10; ++c) { e[c] = __expf(nrm[c] - m); s += e[c]; }
    for (int c = 0; c < 10; ++c) outc[b * 10 + c] = e[c] / s;
    amaxb[b] = am;
  }
}

// ---------- fc1 sparse: d1 = relu(z @ w1 + b1), z has 16 nonzeros/row -------
__global__ __launch_bounds__(256) void fc1s_kernel(
    const float* __restrict__ v, const int* __restrict__ amaxb,
    const float* __restrict__ w, const float* __restrict__ bias,
    float* __restrict__ out) {
  int n  = blockIdx.x * 256 + threadIdx.x;
  int b0 = blockIdx.y * 8;
  __shared__ float vls[8][16];
  __shared__ int ams[8];
  int t = threadIdx.x;
  if (t < 8) ams[t] = amaxb[b0 + t];
  __syncthreads();
  if (t < 128) {
    int bb = t >> 4, oo = t & 15;
    vls[bb][oo] = v[((b0 + bb) * 10 + ams[bb]) * 16 + oo];
  }
  __syncthreads();
  float bv = bias[n];
#pragma unroll
  for (int bb = 0; bb < 8; ++bb) {
    int row0 = ams[bb] * 16;
    float acc = bv;
#pragma unroll
    for (int oo = 0; oo < 16; ++oo)
      acc += vls[bb][oo] * w[(size_t)(row0 + oo) * 1024 + n];
    out[(size_t)(b0 + bb) * 1024 + n] = fmaxf(acc, 0.f);
  }
}

// ---------- split-K FC: partial over K-chunk -> pbuf[kz][32][N] -------------
template <int K, int KCH>
__global__ __launch_bounds__(256) void fcsplit_kernel(
    const float* __restrict__ in, const float* __restrict__ w,
    float* __restrict__ pbuf, int N) {
  int n  = blockIdx.x * 256 + threadIdx.x;
  int b0 = blockIdx.y * 8;
  int k0 = blockIdx.z * KCH;
  __shared__ __align__(16) float inl[KCH * 8];  // [k][bb]
  for (int idx = threadIdx.x; idx < 8 * KCH; idx += 256) {
    int bb = idx / KCH, k = idx - bb * KCH;
    inl[k * 8 + bb] = in[(size_t)(b0 + bb) * K + k0 + k];
  }
  __syncthreads();
  float acc[8];
#pragma unroll
  for (int bb = 0; bb < 8; ++bb) acc[bb] = 0.f;
  for (int k = 0; k < KCH; ++k) {
    float wv = w[(size_t)(k0 + k) * N + n];
    const float4 i0 = *reinterpret_cast<const float4*>(&inl[k * 8]);
    const float4 i1 = *reinterpret_cast<const float4*>(&inl[k * 8 + 4]);
    acc[0] += i0.x * wv; acc[1] += i0.y * wv;
    acc[2] += i0.z * wv; acc[3] += i0.w * wv;
    acc[4] += i1.x * wv; acc[5] += i1.y * wv;
    acc[6] += i1.z * wv; acc[7] += i1.w * wv;
  }
#pragma unroll
  for (int bb = 0; bb < 8; ++bb)
    pbuf[((size_t)blockIdx.z * 32 + b0 + bb) * N + n] = acc[bb];
}

// ---------- combine partials + bias + activation ----------------------------
template <int KS, bool RELU, bool SIG>
__global__ void fccomb_kernel(const float* __restrict__ pbuf,
                              const float* __restrict__ bias,
                              float* __restrict__ out, int N) {
  int idx = blockIdx.x * 256 + threadIdx.x;  // b*N + n
  if (idx >= 32 * N) return;
  int b = idx / N, n = idx - b * N;
  float a = bias[n];
#pragma unroll
  for (int kz = 0; kz < KS; ++kz) a += pbuf[((size_t)kz * 32 + b) * N + n];
  if (RELU) a = fmaxf(a, 0.f);
  if (SIG)  a = 1.f / (1.f + __expf(-a));
  out[idx] = a;
}

// ---------------------------------------------------------------------------
extern "C" void kernel_launch(void* const* d_in, const int* in_sizes, int n_in,
                              void* d_out, int out_size, void* d_ws,
                              size_t ws_size, hipStream_t stream) {
  const float* x       = (const float*)d_in[0];
  const float* conv0_w = (const float*)d_in[1];
  const float* conv0_b = (const float*)d_in[2];
  const float* conv1_w = (const float*)d_in[3];
  const float* conv1_b = (const float*)d_in[4];
  const float* prim_w  = (const float*)d_in[5];
  const float* prim_b  = (const float*)d_in[6];
  const float* W1      = (const float*)d_in[7];
  const float* W2      = (const float*)d_in[8];
  const float* dec_w1  = (const float*)d_in[9];
  const float* dec_b1  = (const float*)d_in[10];
  const float* dec_w2  = (const float*)d_in[11];
  const float* dec_b2  = (const float*)d_in[12];
  const float* dec_w3  = (const float*)d_in[13];
  const float* dec_b3  = (const float*)d_in[14];
  float* out = (float*)d_out;

  f16* wA    = (f16*)d_ws;           // 5,308,416 halves [81][256][256]
  f16* wB    = wA + 5308416;         // 5,308,416
  f16* h0f   = wB + 5308416;         // 6,193,152  [32][756][256]
  f16* h1f   = h0f + 6193152;        // 3,112,960  [32][380][256]
  f16* part1 = h1f + 3112960;        // 12,582,912 [4][32][384][256]
  float* part2 = (float*)part1;      // 3,145,728 f32 (alias; lifetimes ok)
  float* sum2  = part2 + 3145728;    //   393,216 f32 (still inside part1)
  float* caps  = (float*)(part1 + 12582912);  // 294,912
  float* u     = caps + 294912;      //  32,768
  float* vc    = u + 32768;          //   5,120
  int*   amaxb = (int*)(vc + 5120);  //      32
  float* d1    = vc + 5120 + 32;     //  32,768
  float* d2    = d1 + 32768;         //  65,536
  float* pb2   = d2 + 65536;         // 262,144
  float* pb3   = pb2 + 262144;       // 1,048,576

  wprep_kernel<<<2048, 256, 0, stream>>>(conv1_w, wA);
  wprep_kernel<<<2048, 256, 0, stream>>>(prim_w, wB);

  conv0_kernel<<<dim3(NB, 8, 2), 256, 0, stream>>>(x, conv0_w, conv0_b, h0f);

  conv1_mfma<<<dim3(NB, 4, 4), 256, 0, stream>>>(h0f, wA, part1);
  comb1_kernel<<<1520, 256, 0, stream>>>(part1, conv1_b, h1f);

  prim_mfma<<<dim3(16, 2, 8), 256, 0, stream>>>(h1f, wB, part2);
  comb2_kernel<<<1536, 256, 0, stream>>>(part2, sum2);

  prim_squash_kernel<<<(NB * 1152 + 255) / 256, 256, 0, stream>>>(sum2, prim_b,
                                                                  caps);

  routing_kernel<1152, 8>
      <<<dim3(64, NB), 512, 2 * 1152 * sizeof(float), stream>>>(caps, W1, u);
  routing_kernel<64, 16>
      <<<dim3(10, NB), 512, 2 * 64 * sizeof(float), stream>>>(u, W2, vc);

  classes_kernel<<<NB, 64, 0, stream>>>(vc, out, amaxb);

  fc1s_kernel<<<dim3(4, 4), 256, 0, stream>>>(vc, amaxb, dec_w1, dec_b1, d1);

  fcsplit_kernel<1024, 256>
      <<<dim3(8, 4, 4), 256, 0, stream>>>(d1, dec_w2, pb2, 2048);
  fccomb_kernel<4, true, false>
      <<<256, 256, 0, stream>>>(pb2, dec_b2, d2, 2048);

  fcsplit_kernel<2048, 256>
      <<<dim3(16, 4, 8), 256, 0, stream>>>(d2, dec_w3, pb3, 4096);
  fccomb_kernel<8, false, true>
      <<<512, 256, 0, stream>>>(pb3, dec_b3, out + 320, 4096);
}

// Round 5
// 511.167 us; speedup vs baseline: 14.1304x; 1.1921x over previous
//
#include <hip/hip_runtime.h>
#include <hip/hip_bf16.h>
#include <math.h>

// ---------------------------------------------------------------------------
// CapsuleNet forward. Round 5: routing1 split into priors-materialization
// (W read once, f16 priors to HBM) + iterate pass (coalesced prior loads).
// Convs stay fp16 MFMA implicit-GEMM.
// ---------------------------------------------------------------------------

#define NB 32  // batch

typedef _Float16 f16;
typedef f16 f16x2 __attribute__((ext_vector_type(2)));
typedef f16 f16x4 __attribute__((ext_vector_type(4)));
typedef f16 f16x8 __attribute__((ext_vector_type(8)));
typedef float f32x4 __attribute__((ext_vector_type(4)));

// ---------- weight prep: w[oc][ic][81] fp32 -> wo[tap][oc][ic] f16 ----------
__global__ void wprep_kernel(const float* __restrict__ w,
                             f16* __restrict__ wo) {
  for (int j = blockIdx.x * blockDim.x + threadIdx.x; j < 81 * 256 * 256;
       j += gridDim.x * blockDim.x) {
    int tap = j >> 16, rem = j & 65535;
    int oc = rem >> 8, ic = rem & 255;
    wo[j] = (f16)w[(oc * 256 + ic) * 81 + tap];
  }
}

// ---------- conv0: x[32][1][61][61] -> h0f[32][756][256] f16, k9 s2, relu ---
__global__ __launch_bounds__(256) void conv0_kernel(
    const float* __restrict__ x, const float* __restrict__ w,
    const float* __restrict__ bias, f16* __restrict__ outf) {
  int b = blockIdx.x, ocg = blockIdx.y, z = blockIdx.z;  // grid (32, 8, 2)
  __shared__ float img[61 * 61];
  __shared__ __align__(16) float wl[81][32];  // [k][oc]
  int t = threadIdx.x;
  for (int i = t; i < 61 * 61; i += 256) img[i] = x[b * 3721 + i];
  for (int i = t; i < 81 * 32; i += 256) {
    int k = i >> 5, oc = i & 31;
    wl[k][oc] = w[(ocg * 32 + oc) * 81 + k];
  }
  __syncthreads();
  int ocs = (t & 7) * 4;  // 8 subgroups * 4 oc
  int pg  = t >> 3;       // 32 position groups
  int oc0 = ocg * 32 + ocs;
  float b0 = bias[oc0 + 0], b1 = bias[oc0 + 1], b2 = bias[oc0 + 2],
        b3 = bias[oc0 + 3];
  for (int p = pg + z * 32; p < 729; p += 64) {
    int oh = p / 27, ow = p - oh * 27;
    float a0 = 0.f, a1 = 0.f, a2 = 0.f, a3 = 0.f;
    const float* ib = &img[oh * 2 * 61 + ow * 2];
#pragma unroll
    for (int kh = 0; kh < 9; ++kh) {
#pragma unroll
      for (int kw = 0; kw < 9; ++kw) {
        float v = ib[kh * 61 + kw];
        const float4 wv =
            *reinterpret_cast<const float4*>(&wl[kh * 9 + kw][ocs]);
        a0 += v * wv.x; a1 += v * wv.y; a2 += v * wv.z; a3 += v * wv.w;
      }
    }
    int po = oh * 28 + ow;
    f16x4 hv;
    hv[0] = (f16)fmaxf(a0 + b0, 0.f);
    hv[1] = (f16)fmaxf(a1 + b1, 0.f);
    hv[2] = (f16)fmaxf(a2 + b2, 0.f);
    hv[3] = (f16)fmaxf(a3 + b3, 0.f);
    *(f16x4*)&outf[((size_t)b * 756 + po) * 256 + oc0] = hv;
  }
}

// ---------- conv1 MFMA: h0f[32][756][256] -> part1[4][32][384][256] f16 -----
__global__ __launch_bounds__(256) void conv1_mfma(
    const f16* __restrict__ xin,  // [32][756][256]
    const f16* __restrict__ wA,   // [81][256][256]
    f16* __restrict__ part) {     // [4][32][384][256]
  int b = blockIdx.x, ocg = blockIdx.y, ksp = blockIdx.z;
  __shared__ __align__(16) f16 blds[784 * 40];  // [pos 28x28][40 pad]
  __shared__ __align__(16) f16 alds[64 * 40];   // [oc][40 pad]
  int t = threadIdx.x;
  int w = t >> 6, lane = t & 63, kg = lane >> 4, ln = lane & 15;
  int pbB[6];
#pragma unroll
  for (int nf = 0; nf < 6; ++nf) {
    int n = w * 96 + nf * 16 + ln;  // [0,384)
    int oh = n / 20, ow = n - oh * 20;
    pbB[nf] = ((oh * 28 + ow) * 40 + kg * 8) * 2;  // byte offset in blds
  }
  int aoffB = (ln * 40 + kg * 8) * 2;
  f32x4 acc[4][6];
#pragma unroll
  for (int m = 0; m < 4; ++m)
#pragma unroll
    for (int nf = 0; nf < 6; ++nf) acc[m][nf] = (f32x4){0.f, 0.f, 0.f, 0.f};

  const f16* xb = xin + (size_t)b * 756 * 256 + ksp * 64;
  for (int icc = 0; icc < 2; ++icc) {
    __syncthreads();  // prior compute done before blds overwrite
    for (int i = t; i < 784 * 4; i += 256) {
      int p28 = i >> 2, q = i & 3;
      int p = (p28 < 756) ? p28 : (p28 - 28);
      f16x8 v = *(const f16x8*)(xb + (size_t)p * 256 + icc * 32 + q * 8);
      *(f16x8*)&blds[p28 * 40 + q * 8] = v;
    }
    for (int tap = 0; tap < 81; ++tap) {
      __syncthreads();
      {  // stage A: 64 oc x 32 ic
        int oc = t >> 2, q = t & 3;
        f16x8 v = *(const f16x8*)(wA +
            ((size_t)tap * 256 + ocg * 64 + oc) * 256 + ksp * 64 +
            icc * 32 + q * 8);
        *(f16x8*)&alds[oc * 40 + q * 8] = v;
      }
      __syncthreads();
      int kh = tap / 9, kw = tap - kh * 9;
      int rowB = (kh * 28 + kw) * 80;  // byte shift for this tap
      f16x8 af[4];
#pragma unroll
      for (int m = 0; m < 4; ++m)
        af[m] = *(const f16x8*)((const char*)alds + m * (16 * 80) + aoffB);
      f16x8 bf[6];
#pragma unroll
      for (int nf = 0; nf < 6; ++nf)
        bf[nf] = *(const f16x8*)((const char*)blds + pbB[nf] + rowB);
#pragma unroll
      for (int m = 0; m < 4; ++m)
#pragma unroll
        for (int nf = 0; nf < 6; ++nf)
          acc[m][nf] = __builtin_amdgcn_mfma_f32_16x16x32_f16(
              af[m], bf[nf], acc[m][nf], 0, 0, 0);
    }
  }
  f16* pout = part + ((size_t)ksp * 32 + b) * 384 * 256 + ocg * 64;
#pragma unroll
  for (int m = 0; m < 4; ++m)
#pragma unroll
    for (int nf = 0; nf < 6; ++nf) {
      int n = w * 96 + nf * 16 + ln;
      int oc = m * 16 + kg * 4;
      f16x4 v;
#pragma unroll
      for (int j = 0; j < 4; ++j) v[j] = (f16)acc[m][nf][j];
      *(f16x4*)(pout + (size_t)n * 256 + oc) = v;
    }
}

// ---------- combine conv1 partials + bias + relu -> h1f[32][380][256] f16 ---
__global__ void comb1_kernel(const f16* __restrict__ part,
                             const float* __restrict__ bias,
                             f16* __restrict__ h1f) {
  int idx = blockIdx.x * 256 + threadIdx.x;  // (b, p, ocq) : 32*380*32
  if (idx >= 32 * 380 * 32) return;
  int ocq = idx & 31, rem = idx >> 5;
  int p = rem % 380, b = rem / 380;
  float a[8];
#pragma unroll
  for (int j = 0; j < 8; ++j) a[j] = bias[ocq * 8 + j];
#pragma unroll
  for (int k = 0; k < 4; ++k) {
    f16x8 v = *(const f16x8*)&part[(((size_t)k * 32 + b) * 384 + p) * 256 +
                                   ocq * 8];
#pragma unroll
    for (int j = 0; j < 8; ++j) a[j] += (float)v[j];
  }
  f16x8 o;
#pragma unroll
  for (int j = 0; j < 8; ++j) o[j] = (f16)fmaxf(a[j], 0.f);
  *(f16x8*)&h1f[((size_t)b * 380 + p) * 256 + ocq * 8] = o;
}

// ---------- prim conv MFMA: h1f -> part2[8][16][96][256] f32 ----------------
__global__ __launch_bounds__(256) void prim_mfma(
    const f16* __restrict__ xin,  // h1f [32][380][256]
    const f16* __restrict__ wB,   // [81][256][256]
    float* __restrict__ part2) {  // [8][16][96][256]
  int ip = blockIdx.x, ocg = blockIdx.y, ksp = blockIdx.z;
  __shared__ __align__(16) f16 blds[768 * 40];  // [2 img][384 rows][40 pad]
  __shared__ __align__(16) f16 alds[128 * 40];
  int t = threadIdx.x;
  int w = t >> 6, lane = t & 63, kg = lane >> 4, ln = lane & 15;
  int mg = w >> 1, ng = w & 1;
  int pb[3];
#pragma unroll
  for (int nf = 0; nf < 3; ++nf) {
    int rem = nf * 16 + ln;  // [0,48)
    int oh6 = rem >> 3, ow6 = rem & 7;
    pb[nf] = ng * 384 + oh6 * 40 + ow6 * 2;
  }
  f32x4 acc[4][3];
#pragma unroll
  for (int m = 0; m < 4; ++m)
#pragma unroll
    for (int nf = 0; nf < 3; ++nf) acc[m][nf] = (f32x4){0.f, 0.f, 0.f, 0.f};

  for (int i = t; i < 768 * 4; i += 256) {
    int pos = i >> 2, q = i & 3;
    int img = pos >= 384;
    int p = pos - img * 384;
    if (p >= 380) p -= 20;
    f16x8 v = *(const f16x8*)(xin +
        ((size_t)(ip * 2 + img) * 380 + p) * 256 + ksp * 32 + q * 8);
    *(f16x8*)&blds[pos * 40 + q * 8] = v;
  }
  for (int tap = 0; tap < 81; ++tap) {
    __syncthreads();
    for (int i = t; i < 512; i += 256) {  // stage A: 128 oc x 32 ic
      int oc = i >> 2, q = i & 3;
      f16x8 v = *(const f16x8*)(wB +
          ((size_t)tap * 256 + ocg * 128 + oc) * 256 + ksp * 32 + q * 8);
      *(f16x8*)&alds[oc * 40 + q * 8] = v;
    }
    __syncthreads();
    int kh = tap / 9, kw = tap - kh * 9;
    int shift = kh * 20 + kw;
    f16x8 af[4];
#pragma unroll
    for (int m = 0; m < 4; ++m)
      af[m] = *(const f16x8*)((const char*)alds +
                              (((mg * 4 + m) * 16 + ln) * 40 + kg * 8) * 2);
    f16x8 bf[3];
#pragma unroll
    for (int nf = 0; nf < 3; ++nf)
      bf[nf] = *(const f16x8*)((const char*)blds +
                               ((pb[nf] + shift) * 40 + kg * 8) * 2);
#pragma unroll
    for (int m = 0; m < 4; ++m)
#pragma unroll
      for (int nf = 0; nf < 3; ++nf)
        acc[m][nf] = __builtin_amdgcn_mfma_f32_16x16x32_f16(
            af[m], bf[nf], acc[m][nf], 0, 0, 0);
  }
  float* pout = part2 + ((size_t)ksp * 16 + ip) * 96 * 256 + ocg * 128;
#pragma unroll
  for (int m = 0; m < 4; ++m)
#pragma unroll
    for (int nf = 0; nf < 3; ++nf) {
      int n = ng * 48 + nf * 16 + ln;
      int oc = (mg * 4 + m) * 16 + kg * 4;
      *(f32x4*)(pout + (size_t)n * 256 + oc) = acc[m][nf];
    }
}

// ---------- sum prim ksplit partials: part2 -> sum2[16][96][256] ------------
__global__ void comb2_kernel(const float* __restrict__ part2,
                             float* __restrict__ sum2) {
  int idx = blockIdx.x * 256 + threadIdx.x;
  if (idx >= 16 * 96 * 256) return;
  float a = 0.f;
#pragma unroll
  for (int k = 0; k < 8; ++k) a += part2[(size_t)k * 393216 + idx];
  sum2[idx] = a;
}

// ---------- prim bias + squash: sum2 -> caps[32][1152][8] -------------------
__global__ void prim_squash_kernel(const float* __restrict__ sum2,
                                   const float* __restrict__ bias,
                                   float* __restrict__ caps) {
  int idx = blockIdx.x * blockDim.x + threadIdx.x;  // b*1152 + r
  if (idx >= NB * 1152) return;
  int b = idx / 1152, r = idx - b * 1152;
  int m = r / 36, s = r - m * 36;
  int oh6 = s / 6, ow6 = s - oh6 * 6;
  int n = (b & 1) * 48 + oh6 * 8 + ow6;
  const float* src = sum2 + ((size_t)(b >> 1) * 96 + n) * 256;
  float tv[8];
  float sn = 0.f;
#pragma unroll
  for (int g = 0; g < 8; ++g) {
    float v = src[g * 32 + m] + bias[g * 32 + m];
    tv[g] = v;
    sn += v * v;
  }
  float sc = sqrtf(sn) / (1.f + sn);
#pragma unroll
  for (int g = 0; g < 8; ++g) caps[idx * 8 + g] = tv[g] * sc;
}

// ---------- priors1: pri[c][b][r][o] f16 = sum_i caps[b,r,i]*W1[c,r,i,o] ----
// grid (64 c, 36 rt); 256 thr: rl = t>>3 (0..31), oq = t&7 (o = 2oq, 2oq+1).
// W held in registers (read exactly once); x tile staged in LDS.
__global__ __launch_bounds__(256) void priors1_kernel(
    const float* __restrict__ x,   // caps [32][1152][8]
    const float* __restrict__ W,   // W1 [64][1152][8][16]
    f16* __restrict__ pri) {       // [64][32][1152][16]
  int c = blockIdx.x, rt = blockIdx.y;
  int r0 = rt * 32;
  __shared__ __align__(16) float xl[32 * 32 * 8];  // [b][rl][i], 32 KB
  int t = threadIdx.x;
  for (int q = t; q < 2048; q += 256) {
    int b = q >> 6, j = q & 63;  // 64 float4 per b
    *(float4*)&xl[b * 256 + j * 4] =
        *(const float4*)&x[(size_t)b * 9216 + r0 * 8 + j * 4];
  }
  int rl = t >> 3, oq = t & 7;
  float w0[8], w1[8];  // W[c][r0+rl][i][2oq], [i][2oq+1]
#pragma unroll
  for (int i = 0; i < 8; ++i) {
    const float2 wv = *(const float2*)&W[
        (((size_t)c * 1152 + r0 + rl) * 8 + i) * 16 + 2 * oq];
    w0[i] = wv.x; w1[i] = wv.y;
  }
  __syncthreads();
  f16* pout = pri + (size_t)c * 32 * 18432 + (r0 + rl) * 16 + 2 * oq;
#pragma unroll 4
  for (int b = 0; b < 32; ++b) {
    const float4 x0 = *(const float4*)&xl[b * 256 + rl * 8];
    const float4 x1 = *(const float4*)&xl[b * 256 + rl * 8 + 4];
    float s0 = x0.x * w0[0] + x0.y * w0[1] + x0.z * w0[2] + x0.w * w0[3] +
               x1.x * w0[4] + x1.y * w0[5] + x1.z * w0[6] + x1.w * w0[7];
    float s1 = x0.x * w1[0] + x0.y * w1[1] + x0.z * w1[2] + x0.w * w1[3] +
               x1.x * w1[4] + x1.y * w1[5] + x1.z * w1[6] + x1.w * w1[7];
    f16x2 hv; hv[0] = (f16)s0; hv[1] = (f16)s1;
    *(f16x2*)(pout + (size_t)b * 18432) = hv;
  }
}

// ---------- route1: 3 routing iterations from materialized f16 priors -------
// grid (64 c, 32 b); 512 thr. Thread t: o = t&15, rhi = t>>4 (0..31).
__global__ __launch_bounds__(512) void route1_kernel(
    const f16* __restrict__ pri,  // [64][32][1152][16]
    float* __restrict__ out) {    // [B][64][16]
  constexpr int R = 1152;
  constexpr int NREG = 36;
  int c = blockIdx.x, b = blockIdx.y;
  __shared__ float lg[R], pr[R];
  __shared__ float redA[8], redB[8];
  __shared__ float sred[8][16];
  __shared__ float vsh[17];
  int t    = threadIdx.x;
  int o    = t & 15;
  int rhi  = t >> 4;   // 0..31
  int wid  = t >> 6;   // 0..7
  int lane = t & 63;
  const f16* pb = pri + ((size_t)c * 32 + b) * (R * 16);

  float prireg[NREG];
#pragma unroll
  for (int k = 0; k < NREG; ++k)  // block reads contiguous 1KB per k
    prireg[k] = (float)pb[(k * 32 + rhi) * 16 + o];
  for (int r = t; r < R; r += 512) lg[r] = 0.f;
  __syncthreads();

  for (int it = 0; it < 3; ++it) {
    float lm = -1e30f;
    for (int r = t; r < R; r += 512) lm = fmaxf(lm, lg[r]);
#pragma unroll
    for (int s2 = 1; s2 <= 32; s2 <<= 1) lm = fmaxf(lm, __shfl_xor(lm, s2));
    if (lane == 0) redA[wid] = lm;
    __syncthreads();
    if (t == 0) {
      float m8 = redA[0];
#pragma unroll
      for (int w = 1; w < 8; ++w) m8 = fmaxf(m8, redA[w]);
      redA[0] = m8;
    }
    __syncthreads();
    float m = redA[0];
    float ls = 0.f;
    for (int r = t; r < R; r += 512) {
      float e = __expf(lg[r] - m);
      pr[r] = e;
      ls += e;
    }
#pragma unroll
    for (int s2 = 1; s2 <= 32; s2 <<= 1) ls += __shfl_xor(ls, s2);
    if (lane == 0) redB[wid] = ls;
    __syncthreads();
    if (t == 0) {
      float s8 = 0.f;
#pragma unroll
      for (int w = 0; w < 8; ++w) s8 += redB[w];
      redB[0] = s8;
    }
    __syncthreads();
    float denom = redB[0];
    float part = 0.f;
#pragma unroll
    for (int k = 0; k < NREG; ++k) part += pr[k * 32 + rhi] * prireg[k];
    part += __shfl_xor(part, 16);
    part += __shfl_xor(part, 32);
    if (lane < 16) sred[wid][lane] = part;
    __syncthreads();
    if (t < 16) {
      float sv = 0.f;
#pragma unroll
      for (int w = 0; w < 8; ++w) sv += sred[w][t];
      vsh[t] = sv / denom;
    }
    __syncthreads();
    if (t == 0) {
      float sn = 0.f;
#pragma unroll
      for (int oo = 0; oo < 16; ++oo) sn += vsh[oo] * vsh[oo];
      vsh[16] = sqrtf(sn) / (1.f + sn);
    }
    __syncthreads();
    if (it < 2) {
      float vo = vsh[o] * vsh[16];
#pragma unroll
      for (int k = 0; k < NREG; ++k) {
        float val = prireg[k] * vo;
        val += __shfl_xor(val, 1);
        val += __shfl_xor(val, 2);
        val += __shfl_xor(val, 4);
        val += __shfl_xor(val, 8);
        if (o == 0) lg[k * 32 + rhi] += val;
      }
      __syncthreads();
    }
  }
  if (t < 16) out[((size_t)b * 64 + c) * 16 + t] = vsh[t] * vsh[16];
}

// ---------- dynamic routing (generic, used for routing2 only) ---------------
template <int R, int CI>
__global__ __launch_bounds__(512) void routing_kernel(
    const float* __restrict__ x,   // [B][R][CI]
    const float* __restrict__ W,   // [C][R][CI][16]
    float* __restrict__ out) {     // [B][C][16]
  constexpr int NREG = R * 16 / 512;
  int c = blockIdx.x, b = blockIdx.y;
  int C = gridDim.x;
  __shared__ float xls[R * CI];
  extern __shared__ float rdyn[];
  float* lg = rdyn;
  float* pr = rdyn + R;
  __shared__ float redA[8], redB[8];
  __shared__ float sred[8][16];
  __shared__ float vsh[17];
  int t    = threadIdx.x;
  int o    = t & 15;
  int rhi  = t >> 4;
  int wid  = t >> 6;
  int lane = t & 63;
  const float* xb = x + (size_t)b * R * CI;
  const float* Wc = W + (size_t)c * R * CI * 16;

  for (int i = t; i < R * CI; i += 512) xls[i] = xb[i];
  for (int r = t; r < R; r += 512) lg[r] = 0.f;
  __syncthreads();

  float pri[NREG];
#pragma unroll
  for (int k = 0; k < NREG; ++k) {
    int r = k * 32 + rhi;
    float s = 0.f;
#pragma unroll
    for (int i = 0; i < CI; ++i)
      s += xls[r * CI + i] * Wc[((size_t)r * CI + i) * 16 + o];
    pri[k] = s;
  }

  for (int it = 0; it < 3; ++it) {
    float lm = -1e30f;
    for (int r = t; r < R; r += 512) lm = fmaxf(lm, lg[r]);
#pragma unroll
    for (int s2 = 1; s2 <= 32; s2 <<= 1) lm = fmaxf(lm, __shfl_xor(lm, s2));
    if (lane == 0) redA[wid] = lm;
    __syncthreads();
    if (t == 0) {
      float m8 = redA[0];
#pragma unroll
      for (int w = 1; w < 8; ++w) m8 = fmaxf(m8, redA[w]);
      redA[0] = m8;
    }
    __syncthreads();
    float m = redA[0];
    float ls = 0.f;
    for (int r = t; r < R; r += 512) {
      float e = __expf(lg[r] - m);
      pr[r] = e;
      ls += e;
    }
#pragma unroll
    for (int s2 = 1; s2 <= 32; s2 <<= 1) ls += __shfl_xor(ls, s2);
    if (lane == 0) redB[wid] = ls;
    __syncthreads();
    if (t == 0) {
      float s8 = 0.f;
#pragma unroll
      for (int w = 0; w < 8; ++w) s8 += redB[w];
      redB[0] = s8;
    }
    __syncthreads();
    float denom = redB[0];
    float part = 0.f;
#pragma unroll
    for (int k = 0; k < NREG; ++k) part += pr[k * 32 + rhi] * pri[k];
    part += __shfl_xor(part, 16);
    part += __shfl_xor(part, 32);
    if (lane < 16) sred[wid][lane] = part;
    __syncthreads();
    if (t < 16) {
      float sv = 0.f;
#pragma unroll
      for (int w = 0; w < 8; ++w) sv += sred[w][t];
      vsh[t] = sv / denom;
    }
    __syncthreads();
    if (t == 0) {
      float sn = 0.f;
#pragma unroll
      for (int oo = 0; oo < 16; ++oo) sn += vsh[oo] * vsh[oo];
      vsh[16] = sqrtf(sn) / (1.f + sn);
    }
    __syncthreads();
    if (it < 2) {
      float vo = vsh[o] * vsh[16];
#pragma unroll
      for (int k = 0; k < NREG; ++k) {
        float val = pri[k] * vo;
        val += __shfl_xor(val, 1);
        val += __shfl_xor(val, 2);
        val += __shfl_xor(val, 4);
        val += __shfl_xor(val, 8);
        if (o == 0) lg[k * 32 + rhi] += val;
      }
      __syncthreads();
    }
  }
  if (t < 16) out[((size_t)b * C + c) * 16 + t] = vsh[t] * vsh[16];
}

// ---------- classes: norms -> softmax -> argmax index -----------------------
__global__ void classes_kernel(const float* __restrict__ v,
                               float* __restrict__ outc,
                               int* __restrict__ amaxb) {
  int b = blockIdx.x;  // 32 blocks, 64 threads
  int t = threadIdx.x;
  __shared__ float nrm[10];
  if (t < 10) {
    float sn = 0.f;
#pragma unroll
    for (int o = 0; o < 16; ++o) {
      float xv = v[(b * 10 + t) * 16 + o];
      sn += xv * xv;
    }
    nrm[t] = sqrtf(sn);
  }
  __syncthreads();
  if (t == 0) {
    float m = nrm[0];
    int am = 0;
    for (int c = 1; c < 10; ++c)
      if (nrm[c] > m) { m = nrm[c]; am = c; }  // first-max (jnp.argmax)
    float s = 0.f;
    float e[10];
    for (int c = 0; c < 10; ++c) { e[c] = __expf(nrm[c] - m); s += e[c]; }
    for (int c = 0; c < 10; ++c) outc[b * 10 + c] = e[c] / s;
    amaxb[b] = am;
  }
}

// ---------- fc1 sparse: d1 = relu(z @ w1 + b1), z has 16 nonzeros/row -------
__global__ __launch_bounds__(256) void fc1s_kernel(
    const float* __restrict__ v, const int* __restrict__ amaxb,
    const float* __restrict__ w, const float* __restrict__ bias,
    float* __restrict__ out) {
  int n  = blockIdx.x * 256 + threadIdx.x;
  int b0 = blockIdx.y * 8;
  __shared__ float vls[8][16];
  __shared__ int ams[8];
  int t = threadIdx.x;
  if (t < 8) ams[t] = amaxb[b0 + t];
  __syncthreads();
  if (t < 128) {
    int bb = t >> 4, oo = t & 15;
    vls[bb][oo] = v[((b0 + bb) * 10 + ams[bb]) * 16 + oo];
  }
  __syncthreads();
  float bv = bias[n];
#pragma unroll
  for (int bb = 0; bb < 8; ++bb) {
    int row0 = ams[bb] * 16;
    float acc = bv;
#pragma unroll
    for (int oo = 0; oo < 16; ++oo)
      acc += vls[bb][oo] * w[(size_t)(row0 + oo) * 1024 + n];
    out[(size_t)(b0 + bb) * 1024 + n] = fmaxf(acc, 0.f);
  }
}

// ---------- split-K FC: partial over K-chunk -> pbuf[kz][32][N] -------------
template <int K, int KCH>
__global__ __launch_bounds__(256) void fcsplit_kernel(
    const float* __restrict__ in, const float* __restrict__ w,
    float* __restrict__ pbuf, int N) {
  int n  = blockIdx.x * 256 + threadIdx.x;
  int b0 = blockIdx.y * 8;
  int k0 = blockIdx.z * KCH;
  __shared__ __align__(16) float inl[KCH * 8];  // [k][bb]
  for (int idx = threadIdx.x; idx < 8 * KCH; idx += 256) {
    int bb = idx / KCH, k = idx - bb * KCH;
    inl[k * 8 + bb] = in[(size_t)(b0 + bb) * K + k0 + k];
  }
  __syncthreads();
  float acc[8];
#pragma unroll
  for (int bb = 0; bb < 8; ++bb) acc[bb] = 0.f;
  for (int k = 0; k < KCH; ++k) {
    float wv = w[(size_t)(k0 + k) * N + n];
    const float4 i0 = *reinterpret_cast<const float4*>(&inl[k * 8]);
    const float4 i1 = *reinterpret_cast<const float4*>(&inl[k * 8 + 4]);
    acc[0] += i0.x * wv; acc[1] += i0.y * wv;
    acc[2] += i0.z * wv; acc[3] += i0.w * wv;
    acc[4] += i1.x * wv; acc[5] += i1.y * wv;
    acc[6] += i1.z * wv; acc[7] += i1.w * wv;
  }
#pragma unroll
  for (int bb = 0; bb < 8; ++bb)
    pbuf[((size_t)blockIdx.z * 32 + b0 + bb) * N + n] = acc[bb];
}

// ---------- combine partials + bias + activation ----------------------------
template <int KS, bool RELU, bool SIG>
__global__ void fccomb_kernel(const float* __restrict__ pbuf,
                              const float* __restrict__ bias,
                              float* __restrict__ out, int N) {
  int idx = blockIdx.x * 256 + threadIdx.x;  // b*N + n
  if (idx >= 32 * N) return;
  int b = idx / N, n = idx - b * N;
  float a = bias[n];
#pragma unroll
  for (int kz = 0; kz < KS; ++kz) a += pbuf[((size_t)kz * 32 + b) * N + n];
  if (RELU) a = fmaxf(a, 0.f);
  if (SIG)  a = 1.f / (1.f + __expf(-a));
  out[idx] = a;
}

// ---------------------------------------------------------------------------
extern "C" void kernel_launch(void* const* d_in, const int* in_sizes, int n_in,
                              void* d_out, int out_size, void* d_ws,
                              size_t ws_size, hipStream_t stream) {
  const float* x       = (const float*)d_in[0];
  const float* conv0_w = (const float*)d_in[1];
  const float* conv0_b = (const float*)d_in[2];
  const float* conv1_w = (const float*)d_in[3];
  const float* conv1_b = (const float*)d_in[4];
  const float* prim_w  = (const float*)d_in[5];
  const float* prim_b  = (const float*)d_in[6];
  const float* W1      = (const float*)d_in[7];
  const float* W2      = (const float*)d_in[8];
  const float* dec_w1  = (const float*)d_in[9];
  const float* dec_b1  = (const float*)d_in[10];
  const float* dec_w2  = (const float*)d_in[11];
  const float* dec_b2  = (const float*)d_in[12];
  const float* dec_w3  = (const float*)d_in[13];
  const float* dec_b3  = (const float*)d_in[14];
  float* out = (float*)d_out;

  // ---- persistent zone (live across the big transient aliases) ----
  float* ws    = (float*)d_ws;
  float* caps  = ws;                    //   294,912 f  [32][1152][8]
  float* u     = caps + 294912;         //    32,768 f  [32][64][16]
  float* vc    = u + 32768;             //     5,120 f  [32][10][16]
  int*   amaxb = (int*)(vc + 5120);     //        32
  float* trans = vc + 5120 + 32;        // transient zone base (16B aligned)

  // ---- transient zone: conv phase ----
  f16* wA    = (f16*)trans;             //  5,308,416 h [81][256][256]
  f16* wB    = wA + 5308416;            //  5,308,416 h
  f16* h0f   = wB + 5308416;            //  6,193,152 h [32][756][256]
  f16* h1f   = h0f + 6193152;           //  3,112,960 h [32][380][256]
  f16* part1 = h1f + 3112960;           // 12,582,912 h [4][32][384][256]
  float* part2 = (float*)part1;         //  3,145,728 f (alias part1)
  float* sum2  = part2 + 3145728;       //    393,216 f (inside part1)
  // ---- transient zone: routing phase (all conv buffers dead) ----
  f16* pri1  = (f16*)trans;             // 37,748,736 h [64][32][1152][16]
  // ---- transient zone: decoder phase (pri1 dead) ----
  float* d1  = trans;                   //    32,768 f
  float* d2  = d1 + 32768;              //    65,536 f
  float* pb2 = d2 + 65536;              //   262,144 f
  float* pb3 = pb2 + 262144;            // 1,048,576 f

  wprep_kernel<<<2048, 256, 0, stream>>>(conv1_w, wA);
  wprep_kernel<<<2048, 256, 0, stream>>>(prim_w, wB);

  conv0_kernel<<<dim3(NB, 8, 2), 256, 0, stream>>>(x, conv0_w, conv0_b, h0f);

  conv1_mfma<<<dim3(NB, 4, 4), 256, 0, stream>>>(h0f, wA, part1);
  comb1_kernel<<<1520, 256, 0, stream>>>(part1, conv1_b, h1f);

  prim_mfma<<<dim3(16, 2, 8), 256, 0, stream>>>(h1f, wB, part2);
  comb2_kernel<<<1536, 256, 0, stream>>>(part2, sum2);

  prim_squash_kernel<<<(NB * 1152 + 255) / 256, 256, 0, stream>>>(sum2, prim_b,
                                                                  caps);

  // routing1: materialize priors once (W1 read exactly once), then iterate.
  priors1_kernel<<<dim3(64, 36), 256, 0, stream>>>(caps, W1, pri1);
  route1_kernel<<<dim3(64, NB), 512, 0, stream>>>(pri1, u);

  routing_kernel<64, 16>
      <<<dim3(10, NB), 512, 2 * 64 * sizeof(float), stream>>>(u, W2, vc);

  classes_kernel<<<NB, 64, 0, stream>>>(vc, out, amaxb);

  fc1s_kernel<<<dim3(4, 4), 256, 0, stream>>>(vc, amaxb, dec_w1, dec_b1, d1);

  fcsplit_kernel<1024, 256>
      <<<dim3(8, 4, 4), 256, 0, stream>>>(d1, dec_w2, pb2, 2048);
  fccomb_kernel<4, true, false>
      <<<256, 256, 0, stream>>>(pb2, dec_b2, d2, 2048);

  fcsplit_kernel<2048, 256>
      <<<dim3(16, 4, 8), 256, 0, stream>>>(d2, dec_w3, pb3, 4096);
  fccomb_kernel<8, false, true>
      <<<512, 256, 0, stream>>>(pb3, dec_b3, out + 320, 4096);
}

// Round 6
// 484.681 us; speedup vs baseline: 14.9026x; 1.0546x over previous
//
#include <hip/hip_runtime.h>
#include <hip/hip_bf16.h>
#include <math.h>

// ---------------------------------------------------------------------------
// CapsuleNet forward. Round 6: MFMA convs restructured — A operand streamed
// global->register (double-buffered, no per-tap barriers), B-only LDS with
// XOR-swizzled 64B rows (bank-conflict-free); coalesced wprep.
// ---------------------------------------------------------------------------

#define NB 32  // batch

typedef _Float16 f16;
typedef f16 f16x2 __attribute__((ext_vector_type(2)));
typedef f16 f16x4 __attribute__((ext_vector_type(4)));
typedef f16 f16x8 __attribute__((ext_vector_type(8)));
typedef float f32x4 __attribute__((ext_vector_type(4)));

// byte offset into a [row][32 f16] LDS tile (64B rows), 16B slot q in 0..3
__device__ __forceinline__ int swz(int row, int q) {
  return row * 64 + ((q * 16) ^ (((row >> 1) & 3) << 4));
}

// ---------- weight prep: w[oc][ic][81] fp32 -> wo[tap][oc][ic] f16 ----------
// lane = ic (coalesced 128B writes per tap); per-lane 324B row stays L1-hot.
__global__ __launch_bounds__(256) void wprep_kernel(const float* __restrict__ w,
                                                    f16* __restrict__ wo) {
  int idx = blockIdx.x * 256 + threadIdx.x;  // oc*256 + ic
  int oc = idx >> 8, ic = idx & 255;
  const float* src = w + (size_t)(oc * 256 + ic) * 81;
  f16* dst = wo + oc * 256 + ic;
  for (int tap = 0; tap < 81; ++tap)
    dst[(size_t)tap * 65536] = (f16)src[tap];
}

// ---------- conv0: x[32][1][61][61] -> h0f[32][756][256] f16, k9 s2, relu ---
__global__ __launch_bounds__(256) void conv0_kernel(
    const float* __restrict__ x, const float* __restrict__ w,
    const float* __restrict__ bias, f16* __restrict__ outf) {
  int b = blockIdx.x, ocg = blockIdx.y, z = blockIdx.z;  // grid (32, 8, 2)
  __shared__ float img[61 * 61];
  __shared__ __align__(16) float wl[81][32];  // [k][oc]
  int t = threadIdx.x;
  for (int i = t; i < 61 * 61; i += 256) img[i] = x[b * 3721 + i];
  for (int i = t; i < 81 * 32; i += 256) {
    int k = i >> 5, oc = i & 31;
    wl[k][oc] = w[(ocg * 32 + oc) * 81 + k];
  }
  __syncthreads();
  int ocs = (t & 7) * 4;  // 8 subgroups * 4 oc
  int pg  = t >> 3;       // 32 position groups
  int oc0 = ocg * 32 + ocs;
  float b0 = bias[oc0 + 0], b1 = bias[oc0 + 1], b2 = bias[oc0 + 2],
        b3 = bias[oc0 + 3];
  for (int p = pg + z * 32; p < 729; p += 64) {
    int oh = p / 27, ow = p - oh * 27;
    float a0 = 0.f, a1 = 0.f, a2 = 0.f, a3 = 0.f;
    const float* ib = &img[oh * 2 * 61 + ow * 2];
#pragma unroll
    for (int kh = 0; kh < 9; ++kh) {
#pragma unroll
      for (int kw = 0; kw < 9; ++kw) {
        float v = ib[kh * 61 + kw];
        const float4 wv =
            *reinterpret_cast<const float4*>(&wl[kh * 9 + kw][ocs]);
        a0 += v * wv.x; a1 += v * wv.y; a2 += v * wv.z; a3 += v * wv.w;
      }
    }
    int po = oh * 28 + ow;
    f16x4 hv;
    hv[0] = (f16)fmaxf(a0 + b0, 0.f);
    hv[1] = (f16)fmaxf(a1 + b1, 0.f);
    hv[2] = (f16)fmaxf(a2 + b2, 0.f);
    hv[3] = (f16)fmaxf(a3 + b3, 0.f);
    *(f16x4*)&outf[((size_t)b * 756 + po) * 256 + oc0] = hv;
  }
}

// ---------- conv1 MFMA: h0f[32][756][256] -> part1[4][32][384][256] f16 -----
// grid (32 b, 4 ocg, 4 ksp); 256 thr = 4 waves. A: global->reg dbuf; B: LDS.
__global__ __launch_bounds__(256, 2) void conv1_mfma(
    const f16* __restrict__ xin,  // [32][756][256]
    const f16* __restrict__ wA,   // [81][256][256]
    f16* __restrict__ part) {     // [4][32][384][256]
  int b = blockIdx.x, ocg = blockIdx.y, ksp = blockIdx.z;
  __shared__ __align__(16) f16 blds[784 * 32];  // 50176 B, swizzled rows
  int t = threadIdx.x;
  int w = t >> 6, lane = t & 63, kg = lane >> 4, ln = lane & 15;
  int prow[6];
#pragma unroll
  for (int nf = 0; nf < 6; ++nf) {
    int n = w * 96 + nf * 16 + ln;  // [0,384)
    int oh = n / 20, ow = n - oh * 20;
    prow[nf] = oh * 28 + ow;
  }
  f32x4 acc[4][6];
#pragma unroll
  for (int m = 0; m < 4; ++m)
#pragma unroll
    for (int nf = 0; nf < 6; ++nf) acc[m][nf] = (f32x4){0.f, 0.f, 0.f, 0.f};

  const f16* xb = xin + (size_t)b * 756 * 256 + ksp * 64;
  const f16* abase = wA + (size_t)(ocg * 64 + ln) * 256 + ksp * 64 + kg * 8;
  for (int icc = 0; icc < 2; ++icc) {
    __syncthreads();  // all reads of blds from previous icc done
    for (int i = t; i < 3136; i += 256) {
      int p28 = i >> 2, q = i & 3;
      int p = (p28 < 756) ? p28 : (p28 - 28);
      f16x8 v = *(const f16x8*)(xb + (size_t)p * 256 + icc * 32 + q * 8);
      *(f16x8*)((char*)blds + swz(p28, q)) = v;
    }
    const f16* ap = abase + icc * 32;
    f16x8 aN[4];
#pragma unroll
    for (int m = 0; m < 4; ++m) aN[m] = *(const f16x8*)(ap + m * 4096);
    __syncthreads();
#pragma unroll 3
    for (int tap = 0; tap < 81; ++tap) {
      f16x8 aC[4];
#pragma unroll
      for (int m = 0; m < 4; ++m) aC[m] = aN[m];
      // prefetch next tap's A (tap=80 reads into the adjacent ws buffer: ok)
      const f16* apn = ap + (size_t)(tap + 1) * 65536;
#pragma unroll
      for (int m = 0; m < 4; ++m) aN[m] = *(const f16x8*)(apn + m * 4096);
      int kh = tap / 9, kw = tap - kh * 9;
      int shift = kh * 28 + kw;
      f16x8 bf[6];
#pragma unroll
      for (int nf = 0; nf < 6; ++nf)
        bf[nf] = *(const f16x8*)((const char*)blds + swz(prow[nf] + shift, kg));
#pragma unroll
      for (int m = 0; m < 4; ++m)
#pragma unroll
        for (int nf = 0; nf < 6; ++nf)
          acc[m][nf] = __builtin_amdgcn_mfma_f32_16x16x32_f16(
              aC[m], bf[nf], acc[m][nf], 0, 0, 0);
    }
  }
  f16* pout = part + ((size_t)ksp * 32 + b) * 384 * 256 + ocg * 64;
#pragma unroll
  for (int m = 0; m < 4; ++m)
#pragma unroll
    for (int nf = 0; nf < 6; ++nf) {
      int n = w * 96 + nf * 16 + ln;
      int oc = m * 16 + kg * 4;
      f16x4 v;
#pragma unroll
      for (int j = 0; j < 4; ++j) v[j] = (f16)acc[m][nf][j];
      *(f16x4*)(pout + (size_t)n * 256 + oc) = v;
    }
}

// ---------- combine conv1 partials + bias + relu -> h1f[32][380][256] f16 ---
__global__ void comb1_kernel(const f16* __restrict__ part,
                             const float* __restrict__ bias,
                             f16* __restrict__ h1f) {
  int idx = blockIdx.x * 256 + threadIdx.x;  // (b, p, ocq) : 32*380*32
  if (idx >= 32 * 380 * 32) return;
  int ocq = idx & 31, rem = idx >> 5;
  int p = rem % 380, b = rem / 380;
  float a[8];
#pragma unroll
  for (int j = 0; j < 8; ++j) a[j] = bias[ocq * 8 + j];
#pragma unroll
  for (int k = 0; k < 4; ++k) {
    f16x8 v = *(const f16x8*)&part[(((size_t)k * 32 + b) * 384 + p) * 256 +
                                   ocq * 8];
#pragma unroll
    for (int j = 0; j < 8; ++j) a[j] += (float)v[j];
  }
  f16x8 o;
#pragma unroll
  for (int j = 0; j < 8; ++j) o[j] = (f16)fmaxf(a[j], 0.f);
  *(f16x8*)&h1f[((size_t)b * 380 + p) * 256 + ocq * 8] = o;
}

// ---------- prim conv MFMA: h1f -> part2[8][16][96][256] f32 ----------------
// grid (16 img-pair, 2 ocg, 8 ksp); 256 thr. A: global->reg dbuf; B: LDS.
__global__ __launch_bounds__(256, 2) void prim_mfma(
    const f16* __restrict__ xin,  // h1f [32][380][256]
    const f16* __restrict__ wB,   // [81][256][256]
    float* __restrict__ part2) {  // [8][16][96][256]
  int ip = blockIdx.x, ocg = blockIdx.y, ksp = blockIdx.z;
  __shared__ __align__(16) f16 blds[768 * 32];  // 49152 B, swizzled rows
  int t = threadIdx.x;
  int w = t >> 6, lane = t & 63, kg = lane >> 4, ln = lane & 15;
  int mg = w >> 1, ng = w & 1;
  int rbase[3];
#pragma unroll
  for (int nf = 0; nf < 3; ++nf) {
    int rem = nf * 16 + ln;  // [0,48)
    int oh6 = rem >> 3, ow6 = rem & 7;
    rbase[nf] = ng * 384 + oh6 * 40 + ow6 * 2;
  }
  f32x4 acc[4][3];
#pragma unroll
  for (int m = 0; m < 4; ++m)
#pragma unroll
    for (int nf = 0; nf < 3; ++nf) acc[m][nf] = (f32x4){0.f, 0.f, 0.f, 0.f};

  for (int i = t; i < 3072; i += 256) {
    int pos = i >> 2, q = i & 3;
    int img = pos >= 384 ? 1 : 0;
    int p = pos - img * 384;
    if (p >= 380) p -= 20;
    f16x8 v = *(const f16x8*)(xin +
        ((size_t)(ip * 2 + img) * 380 + p) * 256 + ksp * 32 + q * 8);
    *(f16x8*)((char*)blds + swz(pos, q)) = v;
  }
  const f16* abase =
      wB + (size_t)(ocg * 128 + mg * 64 + ln) * 256 + ksp * 32 + kg * 8;
  f16x8 aN[4];
#pragma unroll
  for (int m = 0; m < 4; ++m) aN[m] = *(const f16x8*)(abase + m * 4096);
  __syncthreads();
#pragma unroll 3
  for (int tap = 0; tap < 81; ++tap) {
    f16x8 aC[4];
#pragma unroll
    for (int m = 0; m < 4; ++m) aC[m] = aN[m];
    const f16* apn = abase + (size_t)(tap + 1) * 65536;
#pragma unroll
    for (int m = 0; m < 4; ++m) aN[m] = *(const f16x8*)(apn + m * 4096);
    int kh = tap / 9, kw = tap - kh * 9;
    int shift = kh * 20 + kw;
    f16x8 bf[3];
#pragma unroll
    for (int nf = 0; nf < 3; ++nf)
      bf[nf] = *(const f16x8*)((const char*)blds + swz(rbase[nf] + shift, kg));
#pragma unroll
    for (int m = 0; m < 4; ++m)
#pragma unroll
      for (int nf = 0; nf < 3; ++nf)
        acc[m][nf] = __builtin_amdgcn_mfma_f32_16x16x32_f16(
            aC[m], bf[nf], acc[m][nf], 0, 0, 0);
  }
  float* pout = part2 + ((size_t)ksp * 16 + ip) * 96 * 256 + ocg * 128;
#pragma unroll
  for (int m = 0; m < 4; ++m)
#pragma unroll
    for (int nf = 0; nf < 3; ++nf) {
      int n = ng * 48 + nf * 16 + ln;
      int oc = (mg * 4 + m) * 16 + kg * 4;
      *(f32x4*)(pout + (size_t)n * 256 + oc) = acc[m][nf];
    }
}

// ---------- sum prim ksplit partials: part2 -> sum2[16][96][256] ------------
__global__ void comb2_kernel(const float* __restrict__ part2,
                             float* __restrict__ sum2) {
  int idx = blockIdx.x * 256 + threadIdx.x;
  if (idx >= 16 * 96 * 256) return;
  float a = 0.f;
#pragma unroll
  for (int k = 0; k < 8; ++k) a += part2[(size_t)k * 393216 + idx];
  sum2[idx] = a;
}

// ---------- prim bias + squash: sum2 -> caps[32][1152][8] -------------------
__global__ void prim_squash_kernel(const float* __restrict__ sum2,
                                   const float* __restrict__ bias,
                                   float* __restrict__ caps) {
  int idx = blockIdx.x * blockDim.x + threadIdx.x;  // b*1152 + r
  if (idx >= NB * 1152) return;
  int b = idx / 1152, r = idx - b * 1152;
  int m = r / 36, s = r - m * 36;
  int oh6 = s / 6, ow6 = s - oh6 * 6;
  int n = (b & 1) * 48 + oh6 * 8 + ow6;
  const float* src = sum2 + ((size_t)(b >> 1) * 96 + n) * 256;
  float tv[8];
  float sn = 0.f;
#pragma unroll
  for (int g = 0; g < 8; ++g) {
    float v = src[g * 32 + m] + bias[g * 32 + m];
    tv[g] = v;
    sn += v * v;
  }
  float sc = sqrtf(sn) / (1.f + sn);
#pragma unroll
  for (int g = 0; g < 8; ++g) caps[idx * 8 + g] = tv[g] * sc;
}

// ---------- priors1: pri[c][b][r][o] f16 = sum_i caps[b,r,i]*W1[c,r,i,o] ----
__global__ __launch_bounds__(256) void priors1_kernel(
    const float* __restrict__ x,   // caps [32][1152][8]
    const float* __restrict__ W,   // W1 [64][1152][8][16]
    f16* __restrict__ pri) {       // [64][32][1152][16]
  int c = blockIdx.x, rt = blockIdx.y;
  int r0 = rt * 32;
  __shared__ __align__(16) float xl[32 * 32 * 8];  // [b][rl][i], 32 KB
  int t = threadIdx.x;
  for (int q = t; q < 2048; q += 256) {
    int b = q >> 6, j = q & 63;  // 64 float4 per b
    *(float4*)&xl[b * 256 + j * 4] =
        *(const float4*)&x[(size_t)b * 9216 + r0 * 8 + j * 4];
  }
  int rl = t >> 3, oq = t & 7;
  float w0[8], w1[8];
#pragma unroll
  for (int i = 0; i < 8; ++i) {
    const float2 wv = *(const float2*)&W[
        (((size_t)c * 1152 + r0 + rl) * 8 + i) * 16 + 2 * oq];
    w0[i] = wv.x; w1[i] = wv.y;
  }
  __syncthreads();
  f16* pout = pri + (size_t)c * 32 * 18432 + (r0 + rl) * 16 + 2 * oq;
#pragma unroll 4
  for (int b = 0; b < 32; ++b) {
    const float4 x0 = *(const float4*)&xl[b * 256 + rl * 8];
    const float4 x1 = *(const float4*)&xl[b * 256 + rl * 8 + 4];
    float s0 = x0.x * w0[0] + x0.y * w0[1] + x0.z * w0[2] + x0.w * w0[3] +
               x1.x * w0[4] + x1.y * w0[5] + x1.z * w0[6] + x1.w * w0[7];
    float s1 = x0.x * w1[0] + x0.y * w1[1] + x0.z * w1[2] + x0.w * w1[3] +
               x1.x * w1[4] + x1.y * w1[5] + x1.z * w1[6] + x1.w * w1[7];
    f16x2 hv; hv[0] = (f16)s0; hv[1] = (f16)s1;
    *(f16x2*)(pout + (size_t)b * 18432) = hv;
  }
}

// ---------- route1: 3 routing iterations from materialized f16 priors -------
__global__ __launch_bounds__(512) void route1_kernel(
    const f16* __restrict__ pri,  // [64][32][1152][16]
    float* __restrict__ out) {    // [B][64][16]
  constexpr int R = 1152;
  constexpr int NREG = 36;
  int c = blockIdx.x, b = blockIdx.y;
  __shared__ float lg[R], pr[R];
  __shared__ float redA[8], redB[8];
  __shared__ float sred[8][16];
  __shared__ float vsh[17];
  int t    = threadIdx.x;
  int o    = t & 15;
  int rhi  = t >> 4;   // 0..31
  int wid  = t >> 6;   // 0..7
  int lane = t & 63;
  const f16* pb = pri + ((size_t)c * 32 + b) * (R * 16);

  float prireg[NREG];
#pragma unroll
  for (int k = 0; k < NREG; ++k)
    prireg[k] = (float)pb[(k * 32 + rhi) * 16 + o];
  for (int r = t; r < R; r += 512) lg[r] = 0.f;
  __syncthreads();

  for (int it = 0; it < 3; ++it) {
    float lm = -1e30f;
    for (int r = t; r < R; r += 512) lm = fmaxf(lm, lg[r]);
#pragma unroll
    for (int s2 = 1; s2 <= 32; s2 <<= 1) lm = fmaxf(lm, __shfl_xor(lm, s2));
    if (lane == 0) redA[wid] = lm;
    __syncthreads();
    if (t == 0) {
      float m8 = redA[0];
#pragma unroll
      for (int w = 1; w < 8; ++w) m8 = fmaxf(m8, redA[w]);
      redA[0] = m8;
    }
    __syncthreads();
    float m = redA[0];
    float ls = 0.f;
    for (int r = t; r < R; r += 512) {
      float e = __expf(lg[r] - m);
      pr[r] = e;
      ls += e;
    }
#pragma unroll
    for (int s2 = 1; s2 <= 32; s2 <<= 1) ls += __shfl_xor(ls, s2);
    if (lane == 0) redB[wid] = ls;
    __syncthreads();
    if (t == 0) {
      float s8 = 0.f;
#pragma unroll
      for (int w = 0; w < 8; ++w) s8 += redB[w];
      redB[0] = s8;
    }
    __syncthreads();
    float denom = redB[0];
    float part = 0.f;
#pragma unroll
    for (int k = 0; k < NREG; ++k) part += pr[k * 32 + rhi] * prireg[k];
    part += __shfl_xor(part, 16);
    part += __shfl_xor(part, 32);
    if (lane < 16) sred[wid][lane] = part;
    __syncthreads();
    if (t < 16) {
      float sv = 0.f;
#pragma unroll
      for (int w = 0; w < 8; ++w) sv += sred[w][t];
      vsh[t] = sv / denom;
    }
    __syncthreads();
    if (t == 0) {
      float sn = 0.f;
#pragma unroll
      for (int oo = 0; oo < 16; ++oo) sn += vsh[oo] * vsh[oo];
      vsh[16] = sqrtf(sn) / (1.f + sn);
    }
    __syncthreads();
    if (it < 2) {
      float vo = vsh[o] * vsh[16];
#pragma unroll
      for (int k = 0; k < NREG; ++k) {
        float val = prireg[k] * vo;
        val += __shfl_xor(val, 1);
        val += __shfl_xor(val, 2);
        val += __shfl_xor(val, 4);
        val += __shfl_xor(val, 8);
        if (o == 0) lg[k * 32 + rhi] += val;
      }
      __syncthreads();
    }
  }
  if (t < 16) out[((size_t)b * 64 + c) * 16 + t] = vsh[t] * vsh[16];
}

// ---------- dynamic routing (generic, used for routing2 only) ---------------
template <int R, int CI>
__global__ __launch_bounds__(512) void routing_kernel(
    const float* __restrict__ x,   // [B][R][CI]
    const float* __restrict__ W,   // [C][R][CI][16]
    float* __restrict__ out) {     // [B][C][16]
  constexpr int NREG = R * 16 / 512;
  int c = blockIdx.x, b = blockIdx.y;
  int C = gridDim.x;
  __shared__ float xls[R * CI];
  extern __shared__ float rdyn[];
  float* lg = rdyn;
  float* pr = rdyn + R;
  __shared__ float redA[8], redB[8];
  __shared__ float sred[8][16];
  __shared__ float vsh[17];
  int t    = threadIdx.x;
  int o    = t & 15;
  int rhi  = t >> 4;
  int wid  = t >> 6;
  int lane = t & 63;
  const float* xb = x + (size_t)b * R * CI;
  const float* Wc = W + (size_t)c * R * CI * 16;

  for (int i = t; i < R * CI; i += 512) xls[i] = xb[i];
  for (int r = t; r < R; r += 512) lg[r] = 0.f;
  __syncthreads();

  float pri[NREG];
#pragma unroll
  for (int k = 0; k < NREG; ++k) {
    int r = k * 32 + rhi;
    float s = 0.f;
#pragma unroll
    for (int i = 0; i < CI; ++i)
      s += xls[r * CI + i] * Wc[((size_t)r * CI + i) * 16 + o];
    pri[k] = s;
  }

  for (int it = 0; it < 3; ++it) {
    float lm = -1e30f;
    for (int r = t; r < R; r += 512) lm = fmaxf(lm, lg[r]);
#pragma unroll
    for (int s2 = 1; s2 <= 32; s2 <<= 1) lm = fmaxf(lm, __shfl_xor(lm, s2));
    if (lane == 0) redA[wid] = lm;
    __syncthreads();
    if (t == 0) {
      float m8 = redA[0];
#pragma unroll
      for (int w = 1; w < 8; ++w) m8 = fmaxf(m8, redA[w]);
      redA[0] = m8;
    }
    __syncthreads();
    float m = redA[0];
    float ls = 0.f;
    for (int r = t; r < R; r += 512) {
      float e = __expf(lg[r] - m);
      pr[r] = e;
      ls += e;
    }
#pragma unroll
    for (int s2 = 1; s2 <= 32; s2 <<= 1) ls += __shfl_xor(ls, s2);
    if (lane == 0) redB[wid] = ls;
    __syncthreads();
    if (t == 0) {
      float s8 = 0.f;
#pragma unroll
      for (int w = 0; w < 8; ++w) s8 += redB[w];
      redB[0] = s8;
    }
    __syncthreads();
    float denom = redB[0];
    float part = 0.f;
#pragma unroll
    for (int k = 0; k < NREG; ++k) part += pr[k * 32 + rhi] * pri[k];
    part += __shfl_xor(part, 16);
    part += __shfl_xor(part, 32);
    if (lane < 16) sred[wid][lane] = part;
    __syncthreads();
    if (t < 16) {
      float sv = 0.f;
#pragma unroll
      for (int w = 0; w < 8; ++w) sv += sred[w][t];
      vsh[t] = sv / denom;
    }
    __syncthreads();
    if (t == 0) {
      float sn = 0.f;
#pragma unroll
      for (int oo = 0; oo < 16; ++oo) sn += vsh[oo] * vsh[oo];
      vsh[16] = sqrtf(sn) / (1.f + sn);
    }
    __syncthreads();
    if (it < 2) {
      float vo = vsh[o] * vsh[16];
#pragma unroll
      for (int k = 0; k < NREG; ++k) {
        float val = pri[k] * vo;
        val += __shfl_xor(val, 1);
        val += __shfl_xor(val, 2);
        val += __shfl_xor(val, 4);
        val += __shfl_xor(val, 8);
        if (o == 0) lg[k * 32 + rhi] += val;
      }
      __syncthreads();
    }
  }
  if (t < 16) out[((size_t)b * C + c) * 16 + t] = vsh[t] * vsh[16];
}

// ---------- classes: norms -> softmax -> argmax index -----------------------
__global__ void classes_kernel(const float* __restrict__ v,
                               float* __restrict__ outc,
                               int* __restrict__ amaxb) {
  int b = blockIdx.x;  // 32 blocks, 64 threads
  int t = threadIdx.x;
  __shared__ float nrm[10];
  if (t < 10) {
    float sn = 0.f;
#pragma unroll
    for (int o = 0; o < 16; ++o) {
      float xv = v[(b * 10 + t) * 16 + o];
      sn += xv * xv;
    }
    nrm[t] = sqrtf(sn);
  }
  __syncthreads();
  if (t == 0) {
    float m = nrm[0];
    int am = 0;
    for (int c = 1; c < 10; ++c)
      if (nrm[c] > m) { m = nrm[c]; am = c; }  // first-max (jnp.argmax)
    float s = 0.f;
    float e[10];
    for (int c = 0; c < 10; ++c) { e[c] = __expf(nrm[c] - m); s += e[c]; }
    for (int c = 0; c < 10; ++c) outc[b * 10 + c] = e[c] / s;
    amaxb[b] = am;
  }
}

// ---------- fc1 sparse: d1 = relu(z @ w1 + b1), z has 16 nonzeros/row -------
__global__ __launch_bounds__(256) void fc1s_kernel(
    const float* __restrict__ v, const int* __restrict__ amaxb,
    const float* __restrict__ w, const float* __restrict__ bias,
    float* __restrict__ out) {
  int n  = blockIdx.x * 256 + threadIdx.x;
  int b0 = blockIdx.y * 8;
  __shared__ float vls[8][16];
  __shared__ int ams[8];
  int t = threadIdx.x;
  if (t < 8) ams[t] = amaxb[b0 + t];
  __syncthreads();
  if (t < 128) {
    int bb = t >> 4, oo = t & 15;
    vls[bb][oo] = v[((b0 + bb) * 10 + ams[bb]) * 16 + oo];
  }
  __syncthreads();
  float bv = bias[n];
#pragma unroll
  for (int bb = 0; bb < 8; ++bb) {
    int row0 = ams[bb] * 16;
    float acc = bv;
#pragma unroll
    for (int oo = 0; oo < 16; ++oo)
      acc += vls[bb][oo] * w[(size_t)(row0 + oo) * 1024 + n];
    out[(size_t)(b0 + bb) * 1024 + n] = fmaxf(acc, 0.f);
  }
}

// ---------- split-K FC: partial over K-chunk -> pbuf[kz][32][N] -------------
template <int K, int KCH>
__global__ __launch_bounds__(256) void fcsplit_kernel(
    const float* __restrict__ in, const float* __restrict__ w,
    float* __restrict__ pbuf, int N) {
  int n  = blockIdx.x * 256 + threadIdx.x;
  int b0 = blockIdx.y * 8;
  int k0 = blockIdx.z * KCH;
  __shared__ __align__(16) float inl[KCH * 8];  // [k][bb]
  for (int idx = threadIdx.x; idx < 8 * KCH; idx += 256) {
    int bb = idx / KCH, k = idx - bb * KCH;
    inl[k * 8 + bb] = in[(size_t)(b0 + bb) * K + k0 + k];
  }
  __syncthreads();
  float acc[8];
#pragma unroll
  for (int bb = 0; bb < 8; ++bb) acc[bb] = 0.f;
  for (int k = 0; k < KCH; ++k) {
    float wv = w[(size_t)(k0 + k) * N + n];
    const float4 i0 = *reinterpret_cast<const float4*>(&inl[k * 8]);
    const float4 i1 = *reinterpret_cast<const float4*>(&inl[k * 8 + 4]);
    acc[0] += i0.x * wv; acc[1] += i0.y * wv;
    acc[2] += i0.z * wv; acc[3] += i0.w * wv;
    acc[4] += i1.x * wv; acc[5] += i1.y * wv;
    acc[6] += i1.z * wv; acc[7] += i1.w * wv;
  }
#pragma unroll
  for (int bb = 0; bb < 8; ++bb)
    pbuf[((size_t)blockIdx.z * 32 + b0 + bb) * N + n] = acc[bb];
}

// ---------- combine partials + bias + activation ----------------------------
template <int KS, bool RELU, bool SIG>
__global__ void fccomb_kernel(const float* __restrict__ pbuf,
                              const float* __restrict__ bias,
                              float* __restrict__ out, int N) {
  int idx = blockIdx.x * 256 + threadIdx.x;  // b*N + n
  if (idx >= 32 * N) return;
  int b = idx / N, n = idx - b * N;
  float a = bias[n];
#pragma unroll
  for (int kz = 0; kz < KS; ++kz) a += pbuf[((size_t)kz * 32 + b) * N + n];
  if (RELU) a = fmaxf(a, 0.f);
  if (SIG)  a = 1.f / (1.f + __expf(-a));
  out[idx] = a;
}

// ---------------------------------------------------------------------------
extern "C" void kernel_launch(void* const* d_in, const int* in_sizes, int n_in,
                              void* d_out, int out_size, void* d_ws,
                              size_t ws_size, hipStream_t stream) {
  const float* x       = (const float*)d_in[0];
  const float* conv0_w = (const float*)d_in[1];
  const float* conv0_b = (const float*)d_in[2];
  const float* conv1_w = (const float*)d_in[3];
  const float* conv1_b = (const float*)d_in[4];
  const float* prim_w  = (const float*)d_in[5];
  const float* prim_b  = (const float*)d_in[6];
  const float* W1      = (const float*)d_in[7];
  const float* W2      = (const float*)d_in[8];
  const float* dec_w1  = (const float*)d_in[9];
  const float* dec_b1  = (const float*)d_in[10];
  const float* dec_w2  = (const float*)d_in[11];
  const float* dec_b2  = (const float*)d_in[12];
  const float* dec_w3  = (const float*)d_in[13];
  const float* dec_b3  = (const float*)d_in[14];
  float* out = (float*)d_out;

  // ---- persistent zone ----
  float* ws    = (float*)d_ws;
  float* caps  = ws;                    //   294,912 f  [32][1152][8]
  float* u     = caps + 294912;         //    32,768 f  [32][64][16]
  float* vc    = u + 32768;             //     5,120 f  [32][10][16]
  int*   amaxb = (int*)(vc + 5120);     //        32
  float* trans = vc + 5120 + 32;        // transient zone base

  // ---- transient zone: conv phase ----
  f16* wA    = (f16*)trans;             //  5,308,416 h [81][256][256]
  f16* wB    = wA + 5308416;            //  5,308,416 h (follows wA: tap=81
                                        //   prefetch over-read lands here/h0f)
  f16* h0f   = wB + 5308416;            //  6,193,152 h [32][756][256]
  f16* h1f   = h0f + 6193152;           //  3,112,960 h [32][380][256]
  f16* part1 = h1f + 3112960;           // 12,582,912 h [4][32][384][256]
  float* part2 = (float*)part1;         //  3,145,728 f (alias part1)
  float* sum2  = part2 + 3145728;       //    393,216 f (inside part1)
  // ---- transient zone: routing phase ----
  f16* pri1  = (f16*)trans;             // 37,748,736 h [64][32][1152][16]
  // ---- transient zone: decoder phase ----
  float* d1  = trans;                   //    32,768 f
  float* d2  = d1 + 32768;              //    65,536 f
  float* pb2 = d2 + 65536;              //   262,144 f
  float* pb3 = pb2 + 262144;            // 1,048,576 f

  wprep_kernel<<<256, 256, 0, stream>>>(conv1_w, wA);
  wprep_kernel<<<256, 256, 0, stream>>>(prim_w, wB);

  conv0_kernel<<<dim3(NB, 8, 2), 256, 0, stream>>>(x, conv0_w, conv0_b, h0f);

  conv1_mfma<<<dim3(NB, 4, 4), 256, 0, stream>>>(h0f, wA, part1);
  comb1_kernel<<<1520, 256, 0, stream>>>(part1, conv1_b, h1f);

  prim_mfma<<<dim3(16, 2, 8), 256, 0, stream>>>(h1f, wB, part2);
  comb2_kernel<<<1536, 256, 0, stream>>>(part2, sum2);

  prim_squash_kernel<<<(NB * 1152 + 255) / 256, 256, 0, stream>>>(sum2, prim_b,
                                                                  caps);

  priors1_kernel<<<dim3(64, 36), 256, 0, stream>>>(caps, W1, pri1);
  route1_kernel<<<dim3(64, NB), 512, 0, stream>>>(pri1, u);

  routing_kernel<64, 16>
      <<<dim3(10, NB), 512, 2 * 64 * sizeof(float), stream>>>(u, W2, vc);

  classes_kernel<<<NB, 64, 0, stream>>>(vc, out, amaxb);

  fc1s_kernel<<<dim3(4, 4), 256, 0, stream>>>(vc, amaxb, dec_w1, dec_b1, d1);

  fcsplit_kernel<1024, 256>
      <<<dim3(8, 4, 4), 256, 0, stream>>>(d1, dec_w2, pb2, 2048);
  fccomb_kernel<4, true, false>
      <<<256, 256, 0, stream>>>(pb2, dec_b2, d2, 2048);

  fcsplit_kernel<2048, 256>
      <<<dim3(16, 4, 8), 256, 0, stream>>>(d2, dec_w3, pb3, 4096);
  fccomb_kernel<8, false, true>
      <<<512, 256, 0, stream>>>(pb3, dec_b3, out + 320, 4096);
}